// Round 3
// baseline (291.598 us; speedup 1.0000x reference)
//
#include <hip/hip_runtime.h>
#include <math.h>

// ---------------------------------------------------------------------------
// Face-parallel z-buffer rasterizer, round 3:
//   - faces sorted front-to-back (bitonic, 1 block) so the z-buffer converges
//     early and the read-before-test filter rejects almost all work
//   - per-pixel: read keybuf first; only if our key could win do the exact
//     _rn coverage test (verbatim from the passing round-2 kernel) + atomicMin
// Winner = lexicographic min of (ordered_z_bits, face_index) == reference's
// strict-< chunk scan + argmin-first tie-break. atomicMin is commutative ->
// deterministic output regardless of timing; racy reads are perf-only.
// ---------------------------------------------------------------------------

#define WPF 16    // waves per face (row interleave stride)
#define SORTN 2048

__global__ void setup_kernel(const int* __restrict__ elev,
                             const int* __restrict__ azim,
                             float* __restrict__ R) {
  const float degf = (float)(3.14159265358979323846 / 180.0);
  float e = __fmul_rn((float)(*elev), degf);
  float a = __fmul_rn((float)(*azim), degf);
  float ca = (float)cos((double)a);
  float sa = (float)sin((double)a);
  float ce = (float)cos((double)e);
  float se = (float)sin((double)e);
  // R = rot_y @ rot_x; each entry is a single product (exact vs any matmul order)
  R[0] = ca;   R[1] = __fmul_rn(sa, se); R[2] = __fmul_rn(sa, ce);
  R[3] = 0.0f; R[4] = ce;                R[5] = -se;
  R[6] = -sa;  R[7] = __fmul_rn(ca, se); R[8] = __fmul_rn(ca, ce);
}

__global__ void vertex_kernel(const float* __restrict__ verts,
                              const float* __restrict__ R,
                              float* __restrict__ vx, float* __restrict__ vy,
                              float* __restrict__ vz, float* __restrict__ vtx,
                              float* __restrict__ vty,
                              int N, const int* __restrict__ psize) {
  int i = blockIdx.x * blockDim.x + threadIdx.x;
  if (i >= N) return;
  float a0 = verts[3 * i + 0];
  float a1 = verts[3 * i + 1];
  float a2 = verts[3 * i + 2];
  float r00 = R[0], r01 = R[1], r02 = R[2];
  float r10 = R[3], r11 = R[4], r12 = R[5];
  float r20 = R[6], r21 = R[7], r22 = R[8];
  float x = __fadd_rn(__fadd_rn(__fmul_rn(a0, r00), __fmul_rn(a1, r10)), __fmul_rn(a2, r20));
  float y = __fadd_rn(__fadd_rn(__fmul_rn(a0, r01), __fmul_rn(a1, r11)), __fmul_rn(a2, r21));
  float z = __fadd_rn(__fadd_rn(__fmul_rn(a0, r02), __fmul_rn(a1, r12)), __fmul_rn(a2, r22));
  z = __fadd_rn(z, 2.0f);
  float halfS = (float)((double)(*psize) * 0.5);
  float sx = __fmul_rn(__fadd_rn(__fdiv_rn(x, z), 1.0f), halfS);
  float sy = __fmul_rn(__fadd_rn(__fdiv_rn(y, z), 1.0f), halfS);
  vx[i] = x;
  vy[i] = y;
  vz[i] = z;
  vtx[i] = truncf(sx);
  vty[i] = truncf(sy);
}

// Per-face record: 4x float4 = 64B
//  r0 = {v0x, v0y, v1x, v1y}
//  r1 = {v2x, v2y, x0,  x1 }
//  r2 = {y0,  y1,  inv, bits(zu)}
//  r3 = {bits(iy0), bits(ix0), bits(ix1), 0}
__global__ void face_kernel(const int* __restrict__ faces,
                            const float* __restrict__ vx, const float* __restrict__ vy,
                            const float* __restrict__ vz, const float* __restrict__ vtx,
                            const float* __restrict__ vty,
                            float4* __restrict__ rec, int* __restrict__ nrows,
                            float* __restrict__ colors,
                            int T, const int* __restrict__ psize) {
  int t = blockIdx.x * blockDim.x + threadIdx.x;
  if (t >= T) return;
  int f0 = faces[3 * t + 0];
  int f1 = faces[3 * t + 1];
  int f2 = faces[3 * t + 2];
  float p0x = vx[f0], p0y = vy[f0], p0z = vz[f0];
  float p1x = vx[f1], p1y = vy[f1], p1z = vz[f1];
  float p2x = vx[f2], p2y = vy[f2], p2z = vz[f2];
  float e1x = __fsub_rn(p1x, p0x), e1y = __fsub_rn(p1y, p0y), e1z = __fsub_rn(p1z, p0z);
  float e2x = __fsub_rn(p2x, p0x), e2y = __fsub_rn(p2y, p0y), e2z = __fsub_rn(p2z, p0z);
  float nx = __fsub_rn(__fmul_rn(e1y, e2z), __fmul_rn(e1z, e2y));
  float ny = __fsub_rn(__fmul_rn(e1z, e2x), __fmul_rn(e1x, e2z));
  float nz = __fsub_rn(__fmul_rn(e1x, e2y), __fmul_rn(e1y, e2x));
  float nrm = __fsqrt_rn(__fadd_rn(__fadd_rn(__fmul_rn(nx, nx), __fmul_rn(ny, ny)),
                                   __fmul_rn(nz, nz)));
  float nnz = __fdiv_rn(nz, __fadd_rn(nrm, 1e-8f));
  float cl = fminf(fmaxf(nnz, 0.0f), 1.0f);
  float col = __fadd_rn(__fmul_rn(cl, 180.0f), 75.0f);
  float zf = __fdiv_rn(__fadd_rn(__fadd_rn(p0z, p1z), p2z), 3.0f);
  float t0x = vtx[f0], t0y = vty[f0];
  float t1x = vtx[f1], t1y = vty[f1];
  float t2x = vtx[f2], t2y = vty[f2];
  float cr = __fsub_rn(__fmul_rn(__fsub_rn(t1x, t0x), __fsub_rn(t2y, t0y)),
                       __fmul_rn(__fsub_rn(t2x, t0x), __fsub_rn(t1y, t0y)));
  float area = __fmul_rn(0.5f, fabsf(cr));
  bool valid = (area >= 1e-5f);   // NaN -> false, matches jnp
  float inv = __fdiv_rn(1.0f, __fadd_rn(area, 1e-8f));
  int S = *psize;
  float Sm1 = (float)(S - 1);
  float x0 = fmaxf(0.0f, fminf(fminf(t0x, t1x), t2x));
  float x1 = fminf(Sm1, __fadd_rn(fmaxf(fmaxf(t0x, t1x), t2x), 1.0f));
  float y0 = fmaxf(0.0f, fminf(fminf(t0y, t1y), t2y));
  float y1 = fminf(Sm1, __fadd_rn(fmaxf(fmaxf(t0y, t1y), t2y), 1.0f));
  // ordered z bits: monotonic uint mapping of float z
  unsigned zb = __float_as_uint(zf);
  unsigned zu = (zb & 0x80000000u) ? ~zb : (zb | 0x80000000u);
  // conservative integer bbox (exact float tests re-applied per pixel)
  int nr = 0, iy0 = 0, ix0 = 0, ix1 = -1;
  if (valid) {
    ix0 = (int)fminf(x0, (float)(S + 1));
    ix1 = (int)fmaxf(-1.0f, x1);
    iy0 = (int)fminf(y0, (float)(S + 1));
    int iy1 = (int)fmaxf(-1.0f, y1);
    if (ix0 <= ix1 && iy0 <= iy1) nr = iy1 - iy0 + 1;
  }
  nrows[t] = nr;
  colors[t] = col;
  float4 r0, r1, r2, r3;
  r0.x = t0x; r0.y = t0y; r0.z = t1x; r0.w = t1y;
  r1.x = t2x; r1.y = t2y; r1.z = x0;  r1.w = x1;
  r2.x = y0;  r2.y = y1;  r2.z = inv; r2.w = __uint_as_float(zu);
  r3.x = __int_as_float(iy0); r3.y = __int_as_float(ix0);
  r3.z = __int_as_float(ix1); r3.w = 0.0f;
  rec[4 * t + 0] = r0;
  rec[4 * t + 1] = r1;
  rec[4 * t + 2] = r2;
  rec[4 * t + 3] = r3;
}

// Front-to-back order: bitonic sort (zu, idx) for T <= SORTN faces, 1 block.
__global__ __launch_bounds__(1024) void sort_kernel(const float4* __restrict__ rec,
                                                    int* __restrict__ perm, int T) {
  __shared__ unsigned long long s[SORTN];
  int tid = threadIdx.x;
  if (T > SORTN) {               // fallback: identity order (correctness-only)
    for (int i = tid; i < T; i += 1024) perm[i] = i;
    return;
  }
  for (int i = tid; i < SORTN; i += 1024) {
    unsigned long long k = ~0ULL;
    if (i < T) {
      unsigned zu = __float_as_uint(rec[4 * i + 2].w);
      k = ((unsigned long long)zu << 32) | (unsigned)i;
    }
    s[i] = k;
  }
  __syncthreads();
  for (int k = 2; k <= SORTN; k <<= 1) {
    for (int j = k >> 1; j > 0; j >>= 1) {
      for (int i = tid; i < SORTN; i += 1024) {
        int ixj = i ^ j;
        if (ixj > i) {
          bool up = ((i & k) == 0);
          unsigned long long a = s[i], b = s[ixj];
          if ((a > b) == up) { s[i] = b; s[ixj] = a; }
        }
      }
      __syncthreads();
    }
  }
  for (int i = tid; i < T; i += 1024) perm[i] = (int)(s[i] & 0xFFFFFFFFULL);
}

__global__ __launch_bounds__(256) void raster_kernel(
    const float4* __restrict__ rec, const int* __restrict__ nrows,
    const int* __restrict__ perm, const int* __restrict__ psize,
    unsigned long long* __restrict__ keybuf, int T) {
  int gw = blockIdx.x * (blockDim.x >> 6) + (threadIdx.x >> 6);
  int lane = threadIdx.x & 63;
  int sidx = gw / WPF;
  int widx = gw & (WPF - 1);
  if (sidx >= T) return;
  int f = perm[sidx];
  int nr = nrows[f];
  if (widx >= nr) return;
  int S = *psize;
  float4 r0 = rec[4 * f + 0];
  float4 r1 = rec[4 * f + 1];
  float4 r2 = rec[4 * f + 2];
  float4 r3 = rec[4 * f + 3];
  float v0x = r0.x, v0y = r0.y, v1x = r0.z, v1y = r0.w;
  float v2x = r1.x, v2y = r1.y, x0 = r1.z, x1 = r1.w;
  float y0 = r2.x, y1 = r2.y, inv = r2.z;
  unsigned zu = __float_as_uint(r2.w);
  int iy0 = __float_as_int(r3.x);
  int ix0 = __float_as_int(r3.y);
  int ix1 = __float_as_int(r3.z);
  unsigned long long key = ((unsigned long long)zu << 32) | (unsigned)f;

  for (int r = widx; r < nr; r += WPF) {
    int py_i = iy0 + r;
    float py = (float)py_i;
    if (!(py >= y0 && py < y1)) continue;   // exact inbox-y, wave-uniform
    unsigned long long* rowbuf = keybuf + (size_t)py_i * (size_t)S;
    for (int xb = ix0; xb <= ix1; xb += 64) {
      int px_i = xb + lane;
      // read-first filter: if a strictly smaller key is already stored, our
      // atomicMin could never change the result -> skip the exact test.
      unsigned long long cur = (px_i <= ix1) ? rowbuf[px_i] : 0ULL;
      if (key < cur) {
        float px = (float)px_i;
        // exact reference ops (no FMA): w0 = fl(fl(0.5*|d0|)*inv)
        float d0 = __fsub_rn(__fmul_rn(__fsub_rn(v1x, px), __fsub_rn(v2y, py)),
                             __fmul_rn(__fsub_rn(v2x, px), __fsub_rn(v1y, py)));
        float w0 = __fmul_rn(__fmul_rn(0.5f, fabsf(d0)), inv);
        float d1 = __fsub_rn(__fmul_rn(__fsub_rn(v2x, px), __fsub_rn(v0y, py)),
                             __fmul_rn(__fsub_rn(v0x, px), __fsub_rn(v2y, py)));
        float w1 = __fmul_rn(__fmul_rn(0.5f, fabsf(d1)), inv);
        float w2 = __fsub_rn(__fsub_rn(1.0f, w0), w1);
        bool ok = (w0 >= 0.0f) && (w1 >= 0.0f) && (w2 >= 0.0f) &&
                  (w0 <= 1.0f) && (w1 <= 1.0f) && (w2 <= 1.0f) &&
                  (px >= x0) && (px < x1);    // y-test hoisted above (exact)
        if (ok) atomicMin(rowbuf + px_i, key);
      }
    }
  }
}

__global__ void final_kernel(const unsigned long long* __restrict__ keybuf,
                             const float* __restrict__ colors,
                             float* __restrict__ out,
                             const int* __restrict__ psize) {
  int S = *psize;
  int P = S * S;
  int i = blockIdx.x * blockDim.x + threadIdx.x;
  if (i >= P) return;
  unsigned long long k = keybuf[i];
  float c = (k == 0xFFFFFFFFFFFFFFFFULL)
                ? 255.0f
                : colors[(unsigned)(k & 0xFFFFFFFFULL)];
  out[3 * i + 0] = c;
  out[3 * i + 1] = c;
  out[3 * i + 2] = c;
}

extern "C" void kernel_launch(void* const* d_in, const int* in_sizes, int n_in,
                              void* d_out, int out_size, void* d_ws, size_t ws_size,
                              hipStream_t stream) {
  const float* verts = (const float*)d_in[0];
  const int* faces = (const int*)d_in[1];
  const int* elev = (const int*)d_in[2];
  const int* azim = (const int*)d_in[3];
  const int* psize = (const int*)d_in[4];

  int N = in_sizes[0] / 3;   // 10000
  int T = in_sizes[1] / 3;   // 2048
  const int S_host = 500;    // harness-fixed; kernels use device S for indexing
  const int P = S_host * S_host;

  // ws layout, 64B-aligned sections
  float* wsf = (float*)d_ws;
  size_t off = 0;
  auto alloc = [&](size_t nfloats) {
    float* p = wsf + off;
    off += (nfloats + 15) & ~(size_t)15;
    return p;
  };
  float* R = alloc(16);
  float* vvx = alloc(N);
  float* vvy = alloc(N);
  float* vvz = alloc(N);
  float* vtx = alloc(N);
  float* vty = alloc(N);
  float* colors = alloc(T);
  int* nrows = (int*)alloc(T);
  int* perm = (int*)alloc(T);
  float4* rec = (float4*)alloc((size_t)T * 16);
  unsigned long long* keybuf = (unsigned long long*)alloc((size_t)P * 2);

  setup_kernel<<<1, 1, 0, stream>>>(elev, azim, R);
  vertex_kernel<<<(N + 255) / 256, 256, 0, stream>>>(verts, R, vvx, vvy, vvz, vtx, vty, N, psize);
  face_kernel<<<(T + 255) / 256, 256, 0, stream>>>(faces, vvx, vvy, vvz, vtx, vty,
                                                   rec, nrows, colors, T, psize);
  sort_kernel<<<1, 1024, 0, stream>>>(rec, perm, T);
  hipMemsetAsync(keybuf, 0xFF, (size_t)P * 8, stream);

  // T*WPF waves, 4 waves per 256-thread block; low blockIdx ~ near faces
  int raster_blocks = (T * WPF + 3) / 4;
  raster_kernel<<<raster_blocks, 256, 0, stream>>>(rec, nrows, perm, psize, keybuf, T);

  final_kernel<<<(P + 255) / 256, 256, 0, stream>>>(keybuf, colors, (float*)d_out, psize);
}

// Round 4
// 230.397 us; speedup vs baseline: 1.2656x; 1.2656x over previous
//
#include <hip/hip_runtime.h>
#include <math.h>

// ---------------------------------------------------------------------------
// Tiled, front-to-back, pixel-parallel rasterizer (no atomics, no z-buffer).
// Faces sorted by (ordered_z_bits, idx); per pixel the FIRST covering face in
// sorted order is exactly the reference winner (lexicographic min of
// (z, face_idx) == strict-< chunk scan + argmin-first tie-break; established
// exact in rounds 1-2, absmax 0.0). All decision arithmetic uses the same
// _rn op sequence verbatim. Defensive path: per-pixel 64-bit key min keeps
// correctness even with unsorted lists (early-exit disabled then).
// ---------------------------------------------------------------------------

#define SORTN 4096
#define TILE  16   // 16x16-pixel tiles

__global__ void setup_kernel(const int* __restrict__ elev,
                             const int* __restrict__ azim,
                             float* __restrict__ R) {
  const float degf = (float)(3.14159265358979323846 / 180.0);
  float e = __fmul_rn((float)(*elev), degf);
  float a = __fmul_rn((float)(*azim), degf);
  float ca = (float)cos((double)a);
  float sa = (float)sin((double)a);
  float ce = (float)cos((double)e);
  float se = (float)sin((double)e);
  R[0] = ca;   R[1] = __fmul_rn(sa, se); R[2] = __fmul_rn(sa, ce);
  R[3] = 0.0f; R[4] = ce;                R[5] = -se;
  R[6] = -sa;  R[7] = __fmul_rn(ca, se); R[8] = __fmul_rn(ca, ce);
}

__global__ void vertex_kernel(const float* __restrict__ verts,
                              const float* __restrict__ R,
                              float* __restrict__ vx, float* __restrict__ vy,
                              float* __restrict__ vz, float* __restrict__ vtx,
                              float* __restrict__ vty,
                              int N, const int* __restrict__ psize) {
  int i = blockIdx.x * blockDim.x + threadIdx.x;
  if (i >= N) return;
  float a0 = verts[3 * i + 0];
  float a1 = verts[3 * i + 1];
  float a2 = verts[3 * i + 2];
  float r00 = R[0], r01 = R[1], r02 = R[2];
  float r10 = R[3], r11 = R[4], r12 = R[5];
  float r20 = R[6], r21 = R[7], r22 = R[8];
  float x = __fadd_rn(__fadd_rn(__fmul_rn(a0, r00), __fmul_rn(a1, r10)), __fmul_rn(a2, r20));
  float y = __fadd_rn(__fadd_rn(__fmul_rn(a0, r01), __fmul_rn(a1, r11)), __fmul_rn(a2, r21));
  float z = __fadd_rn(__fadd_rn(__fmul_rn(a0, r02), __fmul_rn(a1, r12)), __fmul_rn(a2, r22));
  z = __fadd_rn(z, 2.0f);
  float halfS = (float)((double)(*psize) * 0.5);
  float sx = __fmul_rn(__fadd_rn(__fdiv_rn(x, z), 1.0f), halfS);
  float sy = __fmul_rn(__fadd_rn(__fdiv_rn(y, z), 1.0f), halfS);
  vx[i] = x;
  vy[i] = y;
  vz[i] = z;
  vtx[i] = truncf(sx);
  vty[i] = truncf(sy);
}

// Per-face record, 4x float4 (64B), indexed by ORIGINAL face id here:
//  r0 = {v0x, v0y, v1x, v1y}
//  r1 = {v2x, v2y, x0,  x1 }
//  r2 = {y0,  y1,  inv, col}
//  r3 = {bits(zu), bits(idx), 0, 0}
__global__ void face_kernel(const int* __restrict__ faces,
                            const float* __restrict__ vx, const float* __restrict__ vy,
                            const float* __restrict__ vz, const float* __restrict__ vtx,
                            const float* __restrict__ vty,
                            float4* __restrict__ fr,
                            unsigned long long* __restrict__ keys,
                            unsigned* __restrict__ span,
                            int T, const int* __restrict__ psize) {
  int t = blockIdx.x * blockDim.x + threadIdx.x;
  if (t >= T) return;
  int f0 = faces[3 * t + 0];
  int f1 = faces[3 * t + 1];
  int f2 = faces[3 * t + 2];
  float p0x = vx[f0], p0y = vy[f0], p0z = vz[f0];
  float p1x = vx[f1], p1y = vy[f1], p1z = vz[f1];
  float p2x = vx[f2], p2y = vy[f2], p2z = vz[f2];
  float e1x = __fsub_rn(p1x, p0x), e1y = __fsub_rn(p1y, p0y), e1z = __fsub_rn(p1z, p0z);
  float e2x = __fsub_rn(p2x, p0x), e2y = __fsub_rn(p2y, p0y), e2z = __fsub_rn(p2z, p0z);
  float nx = __fsub_rn(__fmul_rn(e1y, e2z), __fmul_rn(e1z, e2y));
  float ny = __fsub_rn(__fmul_rn(e1z, e2x), __fmul_rn(e1x, e2z));
  float nz = __fsub_rn(__fmul_rn(e1x, e2y), __fmul_rn(e1y, e2x));
  float nrm = __fsqrt_rn(__fadd_rn(__fadd_rn(__fmul_rn(nx, nx), __fmul_rn(ny, ny)),
                                   __fmul_rn(nz, nz)));
  float nnz = __fdiv_rn(nz, __fadd_rn(nrm, 1e-8f));
  float cl = fminf(fmaxf(nnz, 0.0f), 1.0f);
  float col = __fadd_rn(__fmul_rn(cl, 180.0f), 75.0f);
  float zf = __fdiv_rn(__fadd_rn(__fadd_rn(p0z, p1z), p2z), 3.0f);
  float t0x = vtx[f0], t0y = vty[f0];
  float t1x = vtx[f1], t1y = vty[f1];
  float t2x = vtx[f2], t2y = vty[f2];
  float cr = __fsub_rn(__fmul_rn(__fsub_rn(t1x, t0x), __fsub_rn(t2y, t0y)),
                       __fmul_rn(__fsub_rn(t2x, t0x), __fsub_rn(t1y, t0y)));
  float area = __fmul_rn(0.5f, fabsf(cr));
  bool valid = (area >= 1e-5f);   // NaN -> false, matches jnp
  float inv = __fdiv_rn(1.0f, __fadd_rn(area, 1e-8f));
  int S = *psize;
  float Sm1 = (float)(S - 1);
  float x0 = fmaxf(0.0f, fminf(fminf(t0x, t1x), t2x));
  float x1 = fminf(Sm1, __fadd_rn(fmaxf(fmaxf(t0x, t1x), t2x), 1.0f));
  float y0 = fmaxf(0.0f, fminf(fminf(t0y, t1y), t2y));
  float y1 = fminf(Sm1, __fadd_rn(fmaxf(fmaxf(t0y, t1y), t2y), 1.0f));
  unsigned zb = __float_as_uint(zf);
  unsigned zu = (zb & 0x80000000u) ? ~zb : (zb | 0x80000000u);
  // conservative integer bbox -> tile span (exact float tests redone per px)
  unsigned sp = 0xFFFFFFFFu;   // empty sentinel
  if (valid) {
    int ix0 = (int)fminf(x0, (float)(S + 1));
    int ix1 = (int)fmaxf(-1.0f, x1);
    int iy0 = (int)fminf(y0, (float)(S + 1));
    int iy1 = (int)fmaxf(-1.0f, y1);
    if (ix0 <= ix1 && iy0 <= iy1) {
      unsigned tx0 = (unsigned)(ix0 / TILE), tx1 = (unsigned)(ix1 / TILE);
      unsigned ty0 = (unsigned)(iy0 / TILE), ty1 = (unsigned)(iy1 / TILE);
      sp = tx0 | (ty0 << 5) | (tx1 << 10) | (ty1 << 15);
    }
  }
  keys[t] = ((unsigned long long)zu << 32) | (unsigned)t;
  span[t] = sp;
  float4 r0, r1, r2, r3;
  r0.x = t0x; r0.y = t0y; r0.z = t1x; r0.w = t1y;
  r1.x = t2x; r1.y = t2y; r1.z = x0;  r1.w = x1;
  r2.x = y0;  r2.y = y1;  r2.z = inv; r2.w = col;
  r3.x = __uint_as_float(zu); r3.y = __uint_as_float((unsigned)t);
  r3.z = 0.0f; r3.w = 0.0f;
  fr[4 * t + 0] = r0;
  fr[4 * t + 1] = r1;
  fr[4 * t + 2] = r2;
  fr[4 * t + 3] = r3;
}

// Bitonic sort of (zu, idx) keys, 1 block. perm[s] = original id of s-th face.
__global__ __launch_bounds__(1024) void sort_kernel(const unsigned long long* __restrict__ keys,
                                                    int* __restrict__ perm, int T) {
  __shared__ unsigned long long s[SORTN];
  int tid = threadIdx.x;
  if (T > SORTN) {               // identity fallback (raster stays correct)
    for (int i = tid; i < T; i += 1024) perm[i] = i;
    return;
  }
  for (int i = tid; i < SORTN; i += 1024) s[i] = (i < T) ? keys[i] : ~0ULL;
  __syncthreads();
  for (int k = 2; k <= SORTN; k <<= 1) {
    for (int j = k >> 1; j > 0; j >>= 1) {
      for (int i = tid; i < SORTN; i += 1024) {
        int ixj = i ^ j;
        if (ixj > i) {
          bool up = ((i & k) == 0);
          unsigned long long a = s[i], b = s[ixj];
          if ((a > b) == up) { s[i] = b; s[ixj] = a; }
        }
      }
      __syncthreads();
    }
  }
  for (int i = tid; i < T; i += 1024) perm[i] = (int)(s[i] & 0xFFFFFFFFULL);
}

__global__ void gather_kernel(const float4* __restrict__ fr,
                              const unsigned* __restrict__ span,
                              const int* __restrict__ perm,
                              float4* __restrict__ frs,
                              unsigned* __restrict__ spans_s, int T) {
  int sidx = blockIdx.x * blockDim.x + threadIdx.x;
  if (sidx >= T) return;
  int t = perm[sidx];
  frs[4 * sidx + 0] = fr[4 * t + 0];
  frs[4 * sidx + 1] = fr[4 * t + 1];
  frs[4 * sidx + 2] = fr[4 * t + 2];
  frs[4 * sidx + 3] = fr[4 * t + 3];
  spans_s[sidx] = span[t];
}

// One wave per tile: compact overlapping faces (in sorted order) into list.
__global__ __launch_bounds__(64) void bin_kernel(const unsigned* __restrict__ spans_s,
                                                 unsigned short* __restrict__ lists,
                                                 int* __restrict__ lens,
                                                 int T, int ntx) {
  int tile = blockIdx.x;
  int mytx = tile % ntx, myty = tile / ntx;
  int lane = threadIdx.x;
  unsigned short* list = lists + (size_t)tile * (size_t)T;
  int base = 0;
  for (int g = 0; g < T; g += 64) {
    int sidx = g + lane;
    unsigned sp = (sidx < T) ? spans_s[sidx] : 0xFFFFFFFFu;
    bool ov = false;
    if (sp != 0xFFFFFFFFu) {
      int tx0 = sp & 31, ty0 = (sp >> 5) & 31, tx1 = (sp >> 10) & 31, ty1 = (sp >> 15) & 31;
      ov = (mytx >= tx0) && (mytx <= tx1) && (myty >= ty0) && (myty <= ty1);
    }
    unsigned long long m = __ballot(ov);
    int pos = __popcll(m & ((1ULL << lane) - 1ULL));
    if (ov) list[base + pos] = (unsigned short)sidx;
    base += __popcll(m);
  }
  if (lane == 0) lens[tile] = base;
}

__global__ __launch_bounds__(256) void raster_kernel(
    const float4* __restrict__ frs, const unsigned short* __restrict__ lists,
    const int* __restrict__ lens, const int* __restrict__ psize,
    float* __restrict__ out, int T, int ntx, int sorted_ok) {
  int S = *psize;
  int tile = blockIdx.x;
  int tx = tile % ntx, ty = tile / ntx;
  int px_i = tx * TILE + (threadIdx.x & (TILE - 1));
  int py_i = ty * TILE + (threadIdx.x / TILE);
  float px = (float)px_i, py = (float)py_i;
  bool inimg = (px_i < S) && (py_i < S);
  unsigned long long bkey = ~0ULL;
  float bcol = 255.0f;
  bool covered = !inimg;   // off-image lanes never block early-exit
  // wave pixel extent (float-exact ints) for cheap wave-uniform reject
  int wrow0 = (threadIdx.x >> 6) * (64 / TILE);
  float wxlo = (float)(tx * TILE), wxhi = (float)(tx * TILE + TILE - 1);
  float wylo = (float)(ty * TILE + wrow0);
  float wyhi = (float)(ty * TILE + wrow0 + (64 / TILE) - 1);

  int len = lens[tile];
  const unsigned short* list = lists + (size_t)tile * (size_t)T;

  float4 r0, r1, r2, r3;
  if (len > 0) {
    int s0 = __builtin_amdgcn_readfirstlane((int)list[0]);
    r0 = frs[4 * s0 + 0]; r1 = frs[4 * s0 + 1];
    r2 = frs[4 * s0 + 2]; r3 = frs[4 * s0 + 3];
  }
  int li = 0;
  while (li < len) {
    float4 c0 = r0, c1 = r1, c2 = r2, c3 = r3;
    int nli = li + 1;
    if (nli < len) {   // prefetch next record while testing current
      int ns = __builtin_amdgcn_readfirstlane((int)list[nli]);
      r0 = frs[4 * ns + 0]; r1 = frs[4 * ns + 1];
      r2 = frs[4 * ns + 2]; r3 = frs[4 * ns + 3];
    }
    float x0 = c1.z, x1 = c1.w, y0 = c2.x, y1 = c2.y;
    // wave-uniform conservative reject (exact-int floats; never flips results)
    bool wskip = (wxhi < x0) || (wxlo >= x1) || (wyhi < y0) || (wylo >= y1);
    if (!__builtin_amdgcn_readfirstlane((int)!wskip)) { li = nli; continue; }
    float v0x = c0.x, v0y = c0.y, v1x = c0.z, v1y = c0.w;
    float v2x = c1.x, v2y = c1.y;
    float inv = c2.z, col = c2.w;
    unsigned zu = __float_as_uint(c3.x);
    unsigned fid = __float_as_uint(c3.y);
    unsigned long long fk = ((unsigned long long)zu << 32) | fid;
    // exact reference ops (no FMA): w0 = fl(fl(0.5*|d0|)*inv)
    float d0 = __fsub_rn(__fmul_rn(__fsub_rn(v1x, px), __fsub_rn(v2y, py)),
                         __fmul_rn(__fsub_rn(v2x, px), __fsub_rn(v1y, py)));
    float w0 = __fmul_rn(__fmul_rn(0.5f, fabsf(d0)), inv);
    float d1 = __fsub_rn(__fmul_rn(__fsub_rn(v2x, px), __fsub_rn(v0y, py)),
                         __fmul_rn(__fsub_rn(v0x, px), __fsub_rn(v2y, py)));
    float w1 = __fmul_rn(__fmul_rn(0.5f, fabsf(d1)), inv);
    float w2 = __fsub_rn(__fsub_rn(1.0f, w0), w1);
    bool ok = (w0 >= 0.0f) && (w1 >= 0.0f) && (w2 >= 0.0f) &&
              (w0 <= 1.0f) && (w1 <= 1.0f) && (w2 <= 1.0f) &&
              (px >= x0) && (px < x1) && (py >= y0) && (py < y1);
    bool take = ok && (fk < bkey);   // sorted: equivalent to "first cover"
    bkey = take ? fk : bkey;
    bcol = take ? col : bcol;
    covered = covered || take;
    li = nli;
    if (sorted_ok && __all((int)covered)) break;   // no later face can win
  }
  if (inimg) {
    int o = (py_i * S + px_i) * 3;
    out[o + 0] = bcol;
    out[o + 1] = bcol;
    out[o + 2] = bcol;
  }
}

extern "C" void kernel_launch(void* const* d_in, const int* in_sizes, int n_in,
                              void* d_out, int out_size, void* d_ws, size_t ws_size,
                              hipStream_t stream) {
  const float* verts = (const float*)d_in[0];
  const int* faces = (const int*)d_in[1];
  const int* elev = (const int*)d_in[2];
  const int* azim = (const int*)d_in[3];
  const int* psize = (const int*)d_in[4];

  int N = in_sizes[0] / 3;   // 10000
  int T = in_sizes[1] / 3;   // 2048
  const int S_host = 500;    // harness-fixed; device kernels index via *psize
  const int ntx = (S_host + TILE - 1) / TILE;       // 32
  const int nty = (S_host + TILE - 1) / TILE;       // 32
  const int ntiles = ntx * nty;                     // 1024

  float* wsf = (float*)d_ws;
  size_t off = 0;
  auto alloc = [&](size_t nfloats) {
    float* p = wsf + off;
    off += (nfloats + 15) & ~(size_t)15;
    return p;
  };
  float* R = alloc(16);
  float* vvx = alloc(N);
  float* vvy = alloc(N);
  float* vvz = alloc(N);
  float* vtx = alloc(N);
  float* vty = alloc(N);
  float4* fr = (float4*)alloc((size_t)T * 16);
  float4* frs = (float4*)alloc((size_t)T * 16);
  unsigned long long* keys = (unsigned long long*)alloc((size_t)T * 2);
  unsigned* span = (unsigned*)alloc(T);
  unsigned* spans_s = (unsigned*)alloc(T);
  int* perm = (int*)alloc(T);
  int* lens = (int*)alloc(ntiles);
  unsigned short* lists = (unsigned short*)alloc(((size_t)ntiles * T + 1) / 2);

  setup_kernel<<<1, 1, 0, stream>>>(elev, azim, R);
  vertex_kernel<<<(N + 255) / 256, 256, 0, stream>>>(verts, R, vvx, vvy, vvz, vtx, vty, N, psize);
  face_kernel<<<(T + 255) / 256, 256, 0, stream>>>(faces, vvx, vvy, vvz, vtx, vty,
                                                   fr, keys, span, T, psize);
  sort_kernel<<<1, 1024, 0, stream>>>(keys, perm, T);
  gather_kernel<<<(T + 255) / 256, 256, 0, stream>>>(fr, span, perm, frs, spans_s, T);
  bin_kernel<<<ntiles, 64, 0, stream>>>(spans_s, lists, lens, T, ntx);
  int sorted_ok = (T <= SORTN) ? 1 : 0;
  raster_kernel<<<ntiles, 256, 0, stream>>>(frs, lists, lens, psize,
                                            (float*)d_out, T, ntx, sorted_ok);
}

// Round 5
// 187.778 us; speedup vs baseline: 1.5529x; 1.2270x over previous
//
#include <hip/hip_runtime.h>
#include <math.h>

// ---------------------------------------------------------------------------
// Tiled front-to-back rasterizer, round 5: streaming chunked scan.
// Faces sorted by (ordered_z_bits, idx); per pixel the FIRST covering face in
// sorted order is exactly the reference winner (== lexicographic min of
// (z, face_idx) == strict-< chunk scan + argmin-first; absmax 0.0 in R2-R4).
// Decision arithmetic: identical _rn op sequence, verbatim.
// Raster: per 16x16 tile block, stream all sorted faces through LDS in
// 64-face double-buffered chunks; 64 lanes bbox-test 64 faces in parallel
// (ballot), exact-test only hits via LDS broadcast; per-wave early exit on
// full coverage, per-block exit via __syncthreads_and.
// ---------------------------------------------------------------------------

#define SORTN 2048
#define TILE  16
#define CH    64

__global__ void setup_kernel(const int* __restrict__ elev,
                             const int* __restrict__ azim,
                             float* __restrict__ R) {
  const float degf = (float)(3.14159265358979323846 / 180.0);
  float e = __fmul_rn((float)(*elev), degf);
  float a = __fmul_rn((float)(*azim), degf);
  float ca = (float)cos((double)a);
  float sa = (float)sin((double)a);
  float ce = (float)cos((double)e);
  float se = (float)sin((double)e);
  R[0] = ca;   R[1] = __fmul_rn(sa, se); R[2] = __fmul_rn(sa, ce);
  R[3] = 0.0f; R[4] = ce;                R[5] = -se;
  R[6] = -sa;  R[7] = __fmul_rn(ca, se); R[8] = __fmul_rn(ca, ce);
}

__global__ void vertex_kernel(const float* __restrict__ verts,
                              const float* __restrict__ R,
                              float* __restrict__ vx, float* __restrict__ vy,
                              float* __restrict__ vz, float* __restrict__ vtx,
                              float* __restrict__ vty,
                              int N, const int* __restrict__ psize) {
  int i = blockIdx.x * blockDim.x + threadIdx.x;
  if (i >= N) return;
  float a0 = verts[3 * i + 0];
  float a1 = verts[3 * i + 1];
  float a2 = verts[3 * i + 2];
  float r00 = R[0], r01 = R[1], r02 = R[2];
  float r10 = R[3], r11 = R[4], r12 = R[5];
  float r20 = R[6], r21 = R[7], r22 = R[8];
  float x = __fadd_rn(__fadd_rn(__fmul_rn(a0, r00), __fmul_rn(a1, r10)), __fmul_rn(a2, r20));
  float y = __fadd_rn(__fadd_rn(__fmul_rn(a0, r01), __fmul_rn(a1, r11)), __fmul_rn(a2, r21));
  float z = __fadd_rn(__fadd_rn(__fmul_rn(a0, r02), __fmul_rn(a1, r12)), __fmul_rn(a2, r22));
  z = __fadd_rn(z, 2.0f);
  float halfS = (float)((double)(*psize) * 0.5);
  float sx = __fmul_rn(__fadd_rn(__fdiv_rn(x, z), 1.0f), halfS);
  float sy = __fmul_rn(__fadd_rn(__fdiv_rn(y, z), 1.0f), halfS);
  vx[i] = x;
  vy[i] = y;
  vz[i] = z;
  vtx[i] = truncf(sx);
  vty[i] = truncf(sy);
}

// Per-face record, 4x float4 (64B), original face id:
//  r0 = {v0x, v0y, v1x, v1y}
//  r1 = {v2x, v2y, x0,  x1 }
//  r2 = {y0,  y1,  inv, col}
//  r3 = {bits(zu), bits(idx), valid, 0}
__global__ void face_kernel(const int* __restrict__ faces,
                            const float* __restrict__ vx, const float* __restrict__ vy,
                            const float* __restrict__ vz, const float* __restrict__ vtx,
                            const float* __restrict__ vty,
                            float4* __restrict__ fr,
                            unsigned long long* __restrict__ keys,
                            int T, const int* __restrict__ psize) {
  int t = blockIdx.x * blockDim.x + threadIdx.x;
  if (t >= T) return;
  int f0 = faces[3 * t + 0];
  int f1 = faces[3 * t + 1];
  int f2 = faces[3 * t + 2];
  float p0x = vx[f0], p0y = vy[f0], p0z = vz[f0];
  float p1x = vx[f1], p1y = vy[f1], p1z = vz[f1];
  float p2x = vx[f2], p2y = vy[f2], p2z = vz[f2];
  float e1x = __fsub_rn(p1x, p0x), e1y = __fsub_rn(p1y, p0y), e1z = __fsub_rn(p1z, p0z);
  float e2x = __fsub_rn(p2x, p0x), e2y = __fsub_rn(p2y, p0y), e2z = __fsub_rn(p2z, p0z);
  float nx = __fsub_rn(__fmul_rn(e1y, e2z), __fmul_rn(e1z, e2y));
  float ny = __fsub_rn(__fmul_rn(e1z, e2x), __fmul_rn(e1x, e2z));
  float nz = __fsub_rn(__fmul_rn(e1x, e2y), __fmul_rn(e1y, e2x));
  float nrm = __fsqrt_rn(__fadd_rn(__fadd_rn(__fmul_rn(nx, nx), __fmul_rn(ny, ny)),
                                   __fmul_rn(nz, nz)));
  float nnz = __fdiv_rn(nz, __fadd_rn(nrm, 1e-8f));
  float cl = fminf(fmaxf(nnz, 0.0f), 1.0f);
  float col = __fadd_rn(__fmul_rn(cl, 180.0f), 75.0f);
  float zf = __fdiv_rn(__fadd_rn(__fadd_rn(p0z, p1z), p2z), 3.0f);
  float t0x = vtx[f0], t0y = vty[f0];
  float t1x = vtx[f1], t1y = vty[f1];
  float t2x = vtx[f2], t2y = vty[f2];
  float cr = __fsub_rn(__fmul_rn(__fsub_rn(t1x, t0x), __fsub_rn(t2y, t0y)),
                       __fmul_rn(__fsub_rn(t2x, t0x), __fsub_rn(t1y, t0y)));
  float area = __fmul_rn(0.5f, fabsf(cr));
  bool valid = (area >= 1e-5f);   // NaN -> false, matches jnp
  float inv = __fdiv_rn(1.0f, __fadd_rn(area, 1e-8f));
  int S = *psize;
  float Sm1 = (float)(S - 1);
  float x0 = fmaxf(0.0f, fminf(fminf(t0x, t1x), t2x));
  float x1 = fminf(Sm1, __fadd_rn(fmaxf(fmaxf(t0x, t1x), t2x), 1.0f));
  float y0 = fmaxf(0.0f, fminf(fminf(t0y, t1y), t2y));
  float y1 = fminf(Sm1, __fadd_rn(fmaxf(fmaxf(t0y, t1y), t2y), 1.0f));
  unsigned zb = __float_as_uint(zf);
  unsigned zu = (zb & 0x80000000u) ? ~zb : (zb | 0x80000000u);
  if (!valid) x1 = -3.0e38f;   // exact skip: invalid faces never win a pixel
  keys[t] = ((unsigned long long)zu << 32) | (unsigned)t;
  float4 r0, r1, r2, r3;
  r0.x = t0x; r0.y = t0y; r0.z = t1x; r0.w = t1y;
  r1.x = t2x; r1.y = t2y; r1.z = x0;  r1.w = x1;
  r2.x = y0;  r2.y = y1;  r2.z = inv; r2.w = col;
  r3.x = __uint_as_float(zu); r3.y = __uint_as_float((unsigned)t);
  r3.z = 0.0f; r3.w = 0.0f;
  fr[4 * t + 0] = r0;
  fr[4 * t + 1] = r1;
  fr[4 * t + 2] = r2;
  fr[4 * t + 3] = r3;
}

// Bitonic sort of (zu, idx) + fused gather into sorted record array.
__global__ __launch_bounds__(1024) void sortgather_kernel(
    const unsigned long long* __restrict__ keys, const float4* __restrict__ fr,
    float4* __restrict__ frs, int T) {
  __shared__ unsigned long long s[SORTN];
  int tid = threadIdx.x;
  if (T > SORTN) {   // identity fallback (raster disables early-exit then)
    for (int i = tid; i < 4 * T; i += 1024) frs[i] = fr[i];
    return;
  }
  for (int i = tid; i < SORTN; i += 1024) s[i] = (i < T) ? keys[i] : ~0ULL;
  __syncthreads();
  for (int k = 2; k <= SORTN; k <<= 1) {
    for (int j = k >> 1; j > 0; j >>= 1) {
      for (int i = tid; i < SORTN; i += 1024) {
        int ixj = i ^ j;
        if (ixj > i) {
          bool up = ((i & k) == 0);
          unsigned long long a = s[i], b = s[ixj];
          if ((a > b) == up) { s[i] = b; s[ixj] = a; }
        }
      }
      __syncthreads();
    }
  }
  for (int i = tid; i < T; i += 1024) {
    int t = (int)(s[i] & 0xFFFFFFFFULL);
    frs[4 * i + 0] = fr[4 * t + 0];
    frs[4 * i + 1] = fr[4 * t + 1];
    frs[4 * i + 2] = fr[4 * t + 2];
    frs[4 * i + 3] = fr[4 * t + 3];
  }
}

__global__ __launch_bounds__(256) void raster_kernel(
    const float4* __restrict__ frs, const int* __restrict__ psize,
    float* __restrict__ out, int T, int ntx, int sorted_ok) {
  __shared__ float4 srec[2][CH][4];                       // 8 KiB
  __shared__ float sx0[2][CH], sx1[2][CH];                // 1 KiB
  __shared__ float sy0[2][CH], sy1[2][CH];                // 1 KiB

  int S = *psize;
  int tile = blockIdx.x;
  int tx = tile % ntx, ty = tile / ntx;
  int tid = threadIdx.x;
  int lane = tid & 63;
  int wid = tid >> 6;                      // wave -> rows [4w, 4w+4)
  int col = tid & (TILE - 1);
  int row = tid / TILE;
  int px_i = tx * TILE + col;
  int py_i = ty * TILE + row;
  float px = (float)px_i, py = (float)py_i;
  bool inimg = (px_i < S) && (py_i < S);
  float bcol = 255.0f;
  unsigned long long bkey = ~0ULL;
  bool covered = !inimg;                   // off-image lanes never block exit
  // wave pixel extent (float-exact small ints)
  float wxlo = (float)(tx * TILE), wxhi = (float)(tx * TILE + TILE - 1);
  float wylo = (float)(ty * TILE + wid * 4);
  float wyhi = wylo + 3.0f;

  auto stage = [&](int c, int b) {
    int j = tid >> 2, k = tid & 3;
    int fi = c * CH + j;
    float4 v = make_float4(0.0f, 0.0f, 0.0f, 0.0f);
    if (fi < T) v = frs[4 * fi + k];
    srec[b][j][k] = v;
    if (k == 1) {                          // r1 = {v2x, v2y, x0, x1}
      bool oob = (fi >= T);
      sx0[b][j] = oob ? 3.0e38f : v.z;
      sx1[b][j] = oob ? -3.0e38f : v.w;
    } else if (k == 2) {                   // r2 = {y0, y1, inv, col}
      bool oob = (fi >= T);
      sy0[b][j] = oob ? 3.0e38f : v.x;
      sy1[b][j] = oob ? -3.0e38f : v.y;
    }
  };

  int nch = (T + CH - 1) / CH;
  stage(0, 0);
  bool wdone = (sorted_ok && __all((int)covered));
  for (int c = 0; c < nch; ++c) {
    int b = c & 1;
    __syncthreads();                       // chunk c staged; buf b^1 free
    if (c + 1 < nch) stage(c + 1, b ^ 1);
    if (!wdone) {
      // 64 lanes bbox-test 64 faces in parallel (conflict-free SoA reads)
      bool ov = (wxhi >= sx0[b][lane]) && (wxlo < sx1[b][lane]) &&
                (wyhi >= sy0[b][lane]) && (wylo < sy1[b][lane]);
      unsigned long long m = __ballot(ov);
      while (m) {
        int j = __builtin_ctzll(m);        // ascending = sorted order
        m &= m - 1;
        float4 c0 = srec[b][j][0];         // broadcast reads, conflict-free
        float4 c1 = srec[b][j][1];
        float4 c2 = srec[b][j][2];
        float4 c3 = srec[b][j][3];
        float v0x = c0.x, v0y = c0.y, v1x = c0.z, v1y = c0.w;
        float v2x = c1.x, v2y = c1.y, x0 = c1.z, x1 = c1.w;
        float y0 = c2.x, y1 = c2.y, inv = c2.z, fcol = c2.w;
        // exact reference ops (no FMA): w0 = fl(fl(0.5*|d0|)*inv)
        float d0 = __fsub_rn(__fmul_rn(__fsub_rn(v1x, px), __fsub_rn(v2y, py)),
                             __fmul_rn(__fsub_rn(v2x, px), __fsub_rn(v1y, py)));
        float w0 = __fmul_rn(__fmul_rn(0.5f, fabsf(d0)), inv);
        float d1 = __fsub_rn(__fmul_rn(__fsub_rn(v2x, px), __fsub_rn(v0y, py)),
                             __fmul_rn(__fsub_rn(v0x, px), __fsub_rn(v2y, py)));
        float w1 = __fmul_rn(__fmul_rn(0.5f, fabsf(d1)), inv);
        float w2 = __fsub_rn(__fsub_rn(1.0f, w0), w1);
        bool ok = (w0 >= 0.0f) && (w1 >= 0.0f) && (w2 >= 0.0f) &&
                  (w0 <= 1.0f) && (w1 <= 1.0f) && (w2 <= 1.0f) &&
                  (px >= x0) && (px < x1) && (py >= y0) && (py < y1);
        bool take;
        if (sorted_ok) {
          take = ok && !covered;           // first cover in sorted order wins
        } else {
          unsigned zu = __float_as_uint(c3.x);
          unsigned fid = __float_as_uint(c3.y);
          unsigned long long fk = ((unsigned long long)zu << 32) | fid;
          take = ok && (fk < bkey);
          bkey = take ? fk : bkey;
        }
        bcol = take ? fcol : bcol;
        covered = covered || take;
        if (sorted_ok && __all((int)covered)) { wdone = true; break; }
      }
      if (sorted_ok && !wdone) wdone = __all((int)covered);
    }
    if (__syncthreads_and((int)wdone)) break;   // whole block finished
  }

  if (inimg) {
    int o = (py_i * S + px_i) * 3;
    out[o + 0] = bcol;
    out[o + 1] = bcol;
    out[o + 2] = bcol;
  }
}

extern "C" void kernel_launch(void* const* d_in, const int* in_sizes, int n_in,
                              void* d_out, int out_size, void* d_ws, size_t ws_size,
                              hipStream_t stream) {
  const float* verts = (const float*)d_in[0];
  const int* faces = (const int*)d_in[1];
  const int* elev = (const int*)d_in[2];
  const int* azim = (const int*)d_in[3];
  const int* psize = (const int*)d_in[4];

  int N = in_sizes[0] / 3;   // 10000
  int T = in_sizes[1] / 3;   // 2048
  const int S_host = 500;    // harness-fixed; device kernels index via *psize
  const int ntx = (S_host + TILE - 1) / TILE;       // 32
  const int nty = (S_host + TILE - 1) / TILE;       // 32
  const int ntiles = ntx * nty;                     // 1024

  float* wsf = (float*)d_ws;
  size_t off = 0;
  auto alloc = [&](size_t nfloats) {
    float* p = wsf + off;
    off += (nfloats + 15) & ~(size_t)15;
    return p;
  };
  float* R = alloc(16);
  float* vvx = alloc(N);
  float* vvy = alloc(N);
  float* vvz = alloc(N);
  float* vtx = alloc(N);
  float* vty = alloc(N);
  float4* fr = (float4*)alloc((size_t)T * 16);
  float4* frs = (float4*)alloc((size_t)T * 16);
  unsigned long long* keys = (unsigned long long*)alloc((size_t)T * 2);

  setup_kernel<<<1, 1, 0, stream>>>(elev, azim, R);
  vertex_kernel<<<(N + 255) / 256, 256, 0, stream>>>(verts, R, vvx, vvy, vvz, vtx, vty, N, psize);
  face_kernel<<<(T + 255) / 256, 256, 0, stream>>>(faces, vvx, vvy, vvz, vtx, vty,
                                                   fr, keys, T, psize);
  sortgather_kernel<<<1, 1024, 0, stream>>>(keys, fr, frs, T);
  int sorted_ok = (T <= SORTN) ? 1 : 0;
  raster_kernel<<<ntiles, 256, 0, stream>>>(frs, psize, (float*)d_out, T, ntx, sorted_ok);
}

// Round 6
// 163.599 us; speedup vs baseline: 1.7824x; 1.1478x over previous
//
#include <hip/hip_runtime.h>
#include <math.h>

// ---------------------------------------------------------------------------
// Unsorted, K-split, tile-parallel rasterizer with 64-bit atomicMin resolve.
// Winner per pixel = min over exact-passing faces of (ordered_z_bits<<32)|idx
// == reference's strict-< chunk scan + argmin-first tie-break (absmax 0.0 in
// R2-R5). All decision arithmetic uses the identical _rn op sequence.
// Each (tile, range-segment) block: lane-parallel bbox filter from L2 SoA,
// ballot, 4-way-unrolled hit walk (wave-uniform 64B record broadcasts),
// per-pixel register key min, one read-filtered atomicMin per pixel at end.
// ---------------------------------------------------------------------------

#define TILE 16
#define K    8      // range segments per tile

__device__ __forceinline__ void rot_matrix(int elev, int azim,
                                           float& r00, float& r01, float& r02,
                                           float& r11, float& r12,
                                           float& r20, float& r21, float& r22) {
  const float degf = (float)(3.14159265358979323846 / 180.0);
  float e = __fmul_rn((float)elev, degf);
  float a = __fmul_rn((float)azim, degf);
  float ca = (float)cos((double)a);
  float sa = (float)sin((double)a);
  float ce = (float)cos((double)e);
  float se = (float)sin((double)e);
  // R = rot_y @ rot_x; each entry a single product (exact vs any matmul order)
  r00 = ca;  r01 = __fmul_rn(sa, se); r02 = __fmul_rn(sa, ce);
  r11 = ce;  r12 = -se;
  r20 = -sa; r21 = __fmul_rn(ca, se); r22 = __fmul_rn(ca, ce);
}

__global__ void vertex_kernel(const float* __restrict__ verts,
                              const int* __restrict__ elev,
                              const int* __restrict__ azim,
                              float* __restrict__ vx, float* __restrict__ vy,
                              float* __restrict__ vz, float* __restrict__ vtx,
                              float* __restrict__ vty,
                              int N, const int* __restrict__ psize) {
  int i = blockIdx.x * blockDim.x + threadIdx.x;
  if (i >= N) return;
  float r00, r01, r02, r11, r12, r20, r21, r22;
  rot_matrix(*elev, *azim, r00, r01, r02, r11, r12, r20, r21, r22);
  float a0 = verts[3 * i + 0];
  float a1 = verts[3 * i + 1];
  float a2 = verts[3 * i + 2];
  // vr = v @ R, k-ascending, no FMA: ((m0+m1)+m2); r10 = 0
  float x = __fadd_rn(__fadd_rn(__fmul_rn(a0, r00), __fmul_rn(a1, 0.0f)), __fmul_rn(a2, r20));
  float y = __fadd_rn(__fadd_rn(__fmul_rn(a0, r01), __fmul_rn(a1, r11)), __fmul_rn(a2, r21));
  float z = __fadd_rn(__fadd_rn(__fmul_rn(a0, r02), __fmul_rn(a1, r12)), __fmul_rn(a2, r22));
  z = __fadd_rn(z, 2.0f);
  float halfS = (float)((double)(*psize) * 0.5);
  float sx = __fmul_rn(__fadd_rn(__fdiv_rn(x, z), 1.0f), halfS);
  float sy = __fmul_rn(__fadd_rn(__fdiv_rn(y, z), 1.0f), halfS);
  vx[i] = x;
  vy[i] = y;
  vz[i] = z;
  vtx[i] = truncf(sx);
  vty[i] = truncf(sy);
}

// rec layout (4x float4, 64B): {v0x,v0y,v1x,v1y} {v2x,v2y,x0,x1}
//                              {y0,y1,inv,col}   {bits(zu),bits(idx),0,0}
__global__ void face_kernel(const int* __restrict__ faces,
                            const float* __restrict__ vx, const float* __restrict__ vy,
                            const float* __restrict__ vz, const float* __restrict__ vtx,
                            const float* __restrict__ vty,
                            float4* __restrict__ rec,
                            float* __restrict__ gx0, float* __restrict__ gx1,
                            float* __restrict__ gy0, float* __restrict__ gy1,
                            float* __restrict__ colors,
                            int T, const int* __restrict__ psize) {
  int t = blockIdx.x * blockDim.x + threadIdx.x;
  if (t >= T) return;
  int f0 = faces[3 * t + 0];
  int f1 = faces[3 * t + 1];
  int f2 = faces[3 * t + 2];
  float p0x = vx[f0], p0y = vy[f0], p0z = vz[f0];
  float p1x = vx[f1], p1y = vy[f1], p1z = vz[f1];
  float p2x = vx[f2], p2y = vy[f2], p2z = vz[f2];
  float e1x = __fsub_rn(p1x, p0x), e1y = __fsub_rn(p1y, p0y), e1z = __fsub_rn(p1z, p0z);
  float e2x = __fsub_rn(p2x, p0x), e2y = __fsub_rn(p2y, p0y), e2z = __fsub_rn(p2z, p0z);
  float nx = __fsub_rn(__fmul_rn(e1y, e2z), __fmul_rn(e1z, e2y));
  float ny = __fsub_rn(__fmul_rn(e1z, e2x), __fmul_rn(e1x, e2z));
  float nz = __fsub_rn(__fmul_rn(e1x, e2y), __fmul_rn(e1y, e2x));
  float nrm = __fsqrt_rn(__fadd_rn(__fadd_rn(__fmul_rn(nx, nx), __fmul_rn(ny, ny)),
                                   __fmul_rn(nz, nz)));
  float nnz = __fdiv_rn(nz, __fadd_rn(nrm, 1e-8f));
  float cl = fminf(fmaxf(nnz, 0.0f), 1.0f);
  float col = __fadd_rn(__fmul_rn(cl, 180.0f), 75.0f);
  float zf = __fdiv_rn(__fadd_rn(__fadd_rn(p0z, p1z), p2z), 3.0f);
  float t0x = vtx[f0], t0y = vty[f0];
  float t1x = vtx[f1], t1y = vty[f1];
  float t2x = vtx[f2], t2y = vty[f2];
  float cr = __fsub_rn(__fmul_rn(__fsub_rn(t1x, t0x), __fsub_rn(t2y, t0y)),
                       __fmul_rn(__fsub_rn(t2x, t0x), __fsub_rn(t1y, t0y)));
  float area = __fmul_rn(0.5f, fabsf(cr));
  bool valid = (area >= 1e-5f);   // NaN -> false, matches jnp
  float inv = __fdiv_rn(1.0f, __fadd_rn(area, 1e-8f));
  int S = *psize;
  float Sm1 = (float)(S - 1);
  float x0 = fmaxf(0.0f, fminf(fminf(t0x, t1x), t2x));
  float x1 = fminf(Sm1, __fadd_rn(fmaxf(fmaxf(t0x, t1x), t2x), 1.0f));
  float y0 = fmaxf(0.0f, fminf(fminf(t0y, t1y), t2y));
  float y1 = fminf(Sm1, __fadd_rn(fmaxf(fmaxf(t0y, t1y), t2y), 1.0f));
  unsigned zb = __float_as_uint(zf);
  unsigned zu = (zb & 0x80000000u) ? ~zb : (zb | 0x80000000u);
  if (!valid) x1 = -3.0e38f;   // exact skip: invalid faces never pass px < x1
  gx0[t] = x0; gx1[t] = x1; gy0[t] = y0; gy1[t] = y1;
  colors[t] = col;
  float4 r0, r1, r2, r3;
  r0.x = t0x; r0.y = t0y; r0.z = t1x; r0.w = t1y;
  r1.x = t2x; r1.y = t2y; r1.z = x0;  r1.w = x1;
  r2.x = y0;  r2.y = y1;  r2.z = inv; r2.w = col;
  r3.x = __uint_as_float(zu); r3.y = __uint_as_float((unsigned)t);
  r3.z = 0.0f; r3.w = 0.0f;
  rec[4 * t + 0] = r0;
  rec[4 * t + 1] = r1;
  rec[4 * t + 2] = r2;
  rec[4 * t + 3] = r3;
}

__global__ __launch_bounds__(256) void raster_kernel(
    const float4* __restrict__ rec,
    const float* __restrict__ gx0, const float* __restrict__ gx1,
    const float* __restrict__ gy0, const float* __restrict__ gy1,
    const int* __restrict__ psize,
    unsigned long long* __restrict__ keybuf,
    int T, int ntx, int fpb) {
  int S = *psize;
  int tile = blockIdx.x / K;
  int rseg = blockIdx.x - tile * K;
  int tx = tile % ntx, ty = tile / ntx;
  int tid = threadIdx.x;
  int lane = tid & 63;
  int wid = tid >> 6;                        // wave -> rows [4w, 4w+4)
  int col = tid & (TILE - 1);
  int row = tid / TILE;
  int px_i = tx * TILE + col;
  int py_i = ty * TILE + row;
  float px = (float)px_i, py = (float)py_i;
  bool inimg = (px_i < S) && (py_i < S);
  unsigned long long bkey = ~0ULL;
  // wave pixel extent (float-exact small ints)
  float wxlo = (float)(tx * TILE), wxhi = (float)(tx * TILE + TILE - 1);
  float wylo = (float)(ty * TILE + wid * 4);
  float wyhi = wylo + 3.0f;

  int base = rseg * fpb;
  int lim = min(base + fpb, T);

  for (int g = base; g < lim; g += 64) {
    int fi = g + lane;
    bool in = fi < lim;
    float fx0 = in ? gx0[fi] : 3.0e38f;
    float fx1 = in ? gx1[fi] : -3.0e38f;
    float fy0 = in ? gy0[fi] : 3.0e38f;
    float fy1 = in ? gy1[fi] : -3.0e38f;
    bool ov = (wxhi >= fx0) && (wxlo < fx1) && (wyhi >= fy0) && (wylo < fy1);
    unsigned long long m = __ballot(ov);
    while (m) {
      // extract up to 4 hits; overlap their (wave-uniform) record loads
      int j0 = __builtin_ctzll(m); m &= m - 1;
      int j1 = -1, j2 = -1, j3 = -1;
      if (m) { j1 = __builtin_ctzll(m); m &= m - 1;
        if (m) { j2 = __builtin_ctzll(m); m &= m - 1;
          if (m) { j3 = __builtin_ctzll(m); m &= m - 1; } } }
      const float4* p0 = rec + 4 * (g + j0);
      const float4* p1 = rec + 4 * (g + (j1 >= 0 ? j1 : j0));
      const float4* p2 = rec + 4 * (g + (j2 >= 0 ? j2 : j0));
      const float4* p3 = rec + 4 * (g + (j3 >= 0 ? j3 : j0));
      float4 a0 = p0[0], a1 = p0[1], a2 = p0[2], a3 = p0[3];
      float4 b0 = p1[0], b1 = p1[1], b2 = p1[2], b3 = p1[3];
      float4 c0 = p2[0], c1 = p2[1], c2 = p2[2], c3 = p2[3];
      float4 d0 = p3[0], d1 = p3[1], d2 = p3[2], d3 = p3[3];

#define PROCESS(q0, q1, q2, q3, enable)                                        \
      if (enable) {                                                            \
        float v0x = q0.x, v0y = q0.y, v1x = q0.z, v1y = q0.w;                  \
        float v2x = q1.x, v2y = q1.y, x0 = q1.z, x1 = q1.w;                    \
        float y0 = q2.x, y1 = q2.y, inv = q2.z;                                \
        /* exact reference ops (no FMA): w0 = fl(fl(0.5*|d0|)*inv) */          \
        float e0 = __fsub_rn(__fmul_rn(__fsub_rn(v1x, px), __fsub_rn(v2y, py)),\
                             __fmul_rn(__fsub_rn(v2x, px), __fsub_rn(v1y, py)));\
        float w0 = __fmul_rn(__fmul_rn(0.5f, fabsf(e0)), inv);                 \
        float e1 = __fsub_rn(__fmul_rn(__fsub_rn(v2x, px), __fsub_rn(v0y, py)),\
                             __fmul_rn(__fsub_rn(v0x, px), __fsub_rn(v2y, py)));\
        float w1 = __fmul_rn(__fmul_rn(0.5f, fabsf(e1)), inv);                 \
        float w2 = __fsub_rn(__fsub_rn(1.0f, w0), w1);                         \
        bool ok = (w0 >= 0.0f) && (w1 >= 0.0f) && (w2 >= 0.0f) &&              \
                  (w0 <= 1.0f) && (w1 <= 1.0f) && (w2 <= 1.0f) &&              \
                  (px >= x0) && (px < x1) && (py >= y0) && (py < y1);          \
        unsigned long long fk =                                                \
            ((unsigned long long)__float_as_uint(q3.x) << 32) |                \
            __float_as_uint(q3.y);                                             \
        if (ok && fk < bkey) bkey = fk;                                        \
      }

      PROCESS(a0, a1, a2, a3, true)
      PROCESS(b0, b1, b2, b3, (j1 >= 0))
      PROCESS(c0, c1, c2, c3, (j2 >= 0))
      PROCESS(d0, d1, d2, d3, (j3 >= 0))
#undef PROCESS
    }
  }

  if (inimg && bkey != ~0ULL) {
    unsigned long long* kp = keybuf + ((size_t)py_i * (size_t)S + px_i);
    unsigned long long cur = *kp;     // racy pre-read: filter only
    if (bkey < cur) atomicMin(kp, bkey);
  }
}

__global__ void resolve_kernel(const unsigned long long* __restrict__ keybuf,
                               const float* __restrict__ colors,
                               float* __restrict__ out,
                               const int* __restrict__ psize) {
  int S = *psize;
  int P = S * S;
  int i = blockIdx.x * blockDim.x + threadIdx.x;
  if (i >= P) return;
  unsigned long long k = keybuf[i];
  float c = (k == 0xFFFFFFFFFFFFFFFFULL)
                ? 255.0f
                : colors[(unsigned)(k & 0xFFFFFFFFULL)];
  out[3 * i + 0] = c;
  out[3 * i + 1] = c;
  out[3 * i + 2] = c;
}

extern "C" void kernel_launch(void* const* d_in, const int* in_sizes, int n_in,
                              void* d_out, int out_size, void* d_ws, size_t ws_size,
                              hipStream_t stream) {
  const float* verts = (const float*)d_in[0];
  const int* faces = (const int*)d_in[1];
  const int* elev = (const int*)d_in[2];
  const int* azim = (const int*)d_in[3];
  const int* psize = (const int*)d_in[4];

  int N = in_sizes[0] / 3;   // 10000
  int T = in_sizes[1] / 3;   // 2048
  const int S_host = 500;    // harness-fixed; device kernels index via *psize
  const int P = S_host * S_host;
  const int ntx = (S_host + TILE - 1) / TILE;   // 32
  const int nty = (S_host + TILE - 1) / TILE;   // 32
  const int ntiles = ntx * nty;                 // 1024
  int fpb = (((T + K - 1) / K + 63) / 64) * 64; // faces per range segment

  float* wsf = (float*)d_ws;
  size_t off = 0;
  auto alloc = [&](size_t nfloats) {
    float* p = wsf + off;
    off += (nfloats + 15) & ~(size_t)15;
    return p;
  };
  float* vvx = alloc(N);
  float* vvy = alloc(N);
  float* vvz = alloc(N);
  float* vtx = alloc(N);
  float* vty = alloc(N);
  float* gx0 = alloc(T);
  float* gx1 = alloc(T);
  float* gy0 = alloc(T);
  float* gy1 = alloc(T);
  float* colors = alloc(T);
  float4* rec = (float4*)alloc((size_t)T * 16);
  unsigned long long* keybuf = (unsigned long long*)alloc((size_t)P * 2);

  vertex_kernel<<<(N + 255) / 256, 256, 0, stream>>>(verts, elev, azim,
                                                     vvx, vvy, vvz, vtx, vty, N, psize);
  face_kernel<<<(T + 255) / 256, 256, 0, stream>>>(faces, vvx, vvy, vvz, vtx, vty,
                                                   rec, gx0, gx1, gy0, gy1, colors,
                                                   T, psize);
  hipMemsetAsync(keybuf, 0xFF, (size_t)P * 8, stream);
  raster_kernel<<<ntiles * K, 256, 0, stream>>>(rec, gx0, gx1, gy0, gy1, psize,
                                                keybuf, T, ntx, fpb);
  resolve_kernel<<<(P + 255) / 256, 256, 0, stream>>>(keybuf, colors,
                                                      (float*)d_out, psize);
}

// Round 7
// 117.403 us; speedup vs baseline: 2.4837x; 1.3935x over previous
//
#include <hip/hip_runtime.h>
#include <math.h>

// ---------------------------------------------------------------------------
// Unsorted, K-split, tile-parallel rasterizer with 64-bit atomicMin resolve.
// Winner per pixel = min over exact-passing faces of (ordered_z_bits<<32)|idx
// == reference's strict-< chunk scan + argmin-first tie-break (absmax 0.0,
// R2-R6). Decision arithmetic: identical _rn op sequence, verbatim.
// New in R7: lane-parallel DIAMOND interval filter. The reference coverage is
// {w0<=1 && w1<=1 && w0+w1<=1} (abs-barycentrics -> NOT the triangle), all
// affine-interval-boundable over the wave's clipped strip rectangle via the
// 4 corners of d0, d1, d0+d1, d0-d1 (all affine in (px,py)), with generous
// rounding margins; reject only on proven all-pixels-fail. NaN/overflow -> pass.
// ---------------------------------------------------------------------------

#define TILE 16
#define K    8      // range segments per tile

__device__ __forceinline__ void rot_matrix(int elev, int azim,
                                           float& r00, float& r01, float& r02,
                                           float& r11, float& r12,
                                           float& r20, float& r21, float& r22) {
  const float degf = (float)(3.14159265358979323846 / 180.0);
  float e = __fmul_rn((float)elev, degf);
  float a = __fmul_rn((float)azim, degf);
  float ca = (float)cos((double)a);
  float sa = (float)sin((double)a);
  float ce = (float)cos((double)e);
  float se = (float)sin((double)e);
  // R = rot_y @ rot_x; each entry a single product (exact vs any matmul order)
  r00 = ca;  r01 = __fmul_rn(sa, se); r02 = __fmul_rn(sa, ce);
  r11 = ce;  r12 = -se;
  r20 = -sa; r21 = __fmul_rn(ca, se); r22 = __fmul_rn(ca, ce);
}

__global__ void vertex_kernel(const float* __restrict__ verts,
                              const int* __restrict__ elev,
                              const int* __restrict__ azim,
                              float* __restrict__ vx, float* __restrict__ vy,
                              float* __restrict__ vz, float* __restrict__ vtx,
                              float* __restrict__ vty,
                              int N, const int* __restrict__ psize) {
  int i = blockIdx.x * blockDim.x + threadIdx.x;
  if (i >= N) return;
  float r00, r01, r02, r11, r12, r20, r21, r22;
  rot_matrix(*elev, *azim, r00, r01, r02, r11, r12, r20, r21, r22);
  float a0 = verts[3 * i + 0];
  float a1 = verts[3 * i + 1];
  float a2 = verts[3 * i + 2];
  // vr = v @ R, k-ascending, no FMA: ((m0+m1)+m2); r10 = 0
  float x = __fadd_rn(__fadd_rn(__fmul_rn(a0, r00), __fmul_rn(a1, 0.0f)), __fmul_rn(a2, r20));
  float y = __fadd_rn(__fadd_rn(__fmul_rn(a0, r01), __fmul_rn(a1, r11)), __fmul_rn(a2, r21));
  float z = __fadd_rn(__fadd_rn(__fmul_rn(a0, r02), __fmul_rn(a1, r12)), __fmul_rn(a2, r22));
  z = __fadd_rn(z, 2.0f);
  float halfS = (float)((double)(*psize) * 0.5);
  float sx = __fmul_rn(__fadd_rn(__fdiv_rn(x, z), 1.0f), halfS);
  float sy = __fmul_rn(__fadd_rn(__fdiv_rn(y, z), 1.0f), halfS);
  vx[i] = x;
  vy[i] = y;
  vz[i] = z;
  vtx[i] = truncf(sx);
  vty[i] = truncf(sy);
}

// rec layout (4x float4, 64B): {v0x,v0y,v1x,v1y} {v2x,v2y,x0,x1}
//                              {y0,y1,inv,col}   {bits(zu),bits(idx),0,0}
__global__ void face_kernel(const int* __restrict__ faces,
                            const float* __restrict__ vx, const float* __restrict__ vy,
                            const float* __restrict__ vz, const float* __restrict__ vtx,
                            const float* __restrict__ vty,
                            float4* __restrict__ rec,
                            float* __restrict__ gx0, float* __restrict__ gx1,
                            float* __restrict__ gy0, float* __restrict__ gy1,
                            float* __restrict__ gv0x, float* __restrict__ gv0y,
                            float* __restrict__ gv1x, float* __restrict__ gv1y,
                            float* __restrict__ gv2x, float* __restrict__ gv2y,
                            float* __restrict__ ginv,
                            float* __restrict__ colors,
                            int T, const int* __restrict__ psize) {
  int t = blockIdx.x * blockDim.x + threadIdx.x;
  if (t >= T) return;
  int f0 = faces[3 * t + 0];
  int f1 = faces[3 * t + 1];
  int f2 = faces[3 * t + 2];
  float p0x = vx[f0], p0y = vy[f0], p0z = vz[f0];
  float p1x = vx[f1], p1y = vy[f1], p1z = vz[f1];
  float p2x = vx[f2], p2y = vy[f2], p2z = vz[f2];
  float e1x = __fsub_rn(p1x, p0x), e1y = __fsub_rn(p1y, p0y), e1z = __fsub_rn(p1z, p0z);
  float e2x = __fsub_rn(p2x, p0x), e2y = __fsub_rn(p2y, p0y), e2z = __fsub_rn(p2z, p0z);
  float nx = __fsub_rn(__fmul_rn(e1y, e2z), __fmul_rn(e1z, e2y));
  float ny = __fsub_rn(__fmul_rn(e1z, e2x), __fmul_rn(e1x, e2z));
  float nz = __fsub_rn(__fmul_rn(e1x, e2y), __fmul_rn(e1y, e2x));
  float nrm = __fsqrt_rn(__fadd_rn(__fadd_rn(__fmul_rn(nx, nx), __fmul_rn(ny, ny)),
                                   __fmul_rn(nz, nz)));
  float nnz = __fdiv_rn(nz, __fadd_rn(nrm, 1e-8f));
  float cl = fminf(fmaxf(nnz, 0.0f), 1.0f);
  float col = __fadd_rn(__fmul_rn(cl, 180.0f), 75.0f);
  float zf = __fdiv_rn(__fadd_rn(__fadd_rn(p0z, p1z), p2z), 3.0f);
  float t0x = vtx[f0], t0y = vty[f0];
  float t1x = vtx[f1], t1y = vty[f1];
  float t2x = vtx[f2], t2y = vty[f2];
  float cr = __fsub_rn(__fmul_rn(__fsub_rn(t1x, t0x), __fsub_rn(t2y, t0y)),
                       __fmul_rn(__fsub_rn(t2x, t0x), __fsub_rn(t1y, t0y)));
  float area = __fmul_rn(0.5f, fabsf(cr));
  bool valid = (area >= 1e-5f);   // NaN -> false, matches jnp
  float inv = __fdiv_rn(1.0f, __fadd_rn(area, 1e-8f));
  int S = *psize;
  float Sm1 = (float)(S - 1);
  float x0 = fmaxf(0.0f, fminf(fminf(t0x, t1x), t2x));
  float x1 = fminf(Sm1, __fadd_rn(fmaxf(fmaxf(t0x, t1x), t2x), 1.0f));
  float y0 = fmaxf(0.0f, fminf(fminf(t0y, t1y), t2y));
  float y1 = fminf(Sm1, __fadd_rn(fmaxf(fmaxf(t0y, t1y), t2y), 1.0f));
  unsigned zb = __float_as_uint(zf);
  unsigned zu = (zb & 0x80000000u) ? ~zb : (zb | 0x80000000u);
  if (!valid) x1 = -3.0e38f;   // exact skip: invalid faces never pass px < x1
  gx0[t] = x0; gx1[t] = x1; gy0[t] = y0; gy1[t] = y1;
  gv0x[t] = t0x; gv0y[t] = t0y;
  gv1x[t] = t1x; gv1y[t] = t1y;
  gv2x[t] = t2x; gv2y[t] = t2y;
  ginv[t] = inv;
  colors[t] = col;
  float4 r0, r1, r2, r3;
  r0.x = t0x; r0.y = t0y; r0.z = t1x; r0.w = t1y;
  r1.x = t2x; r1.y = t2y; r1.z = x0;  r1.w = x1;
  r2.x = y0;  r2.y = y1;  r2.z = inv; r2.w = col;
  r3.x = __uint_as_float(zu); r3.y = __uint_as_float((unsigned)t);
  r3.z = 0.0f; r3.w = 0.0f;
  rec[4 * t + 0] = r0;
  rec[4 * t + 1] = r1;
  rec[4 * t + 2] = r2;
  rec[4 * t + 3] = r3;
}

__global__ __launch_bounds__(256) void raster_kernel(
    const float4* __restrict__ rec,
    const float* __restrict__ gx0, const float* __restrict__ gx1,
    const float* __restrict__ gy0, const float* __restrict__ gy1,
    const float* __restrict__ gv0x, const float* __restrict__ gv0y,
    const float* __restrict__ gv1x, const float* __restrict__ gv1y,
    const float* __restrict__ gv2x, const float* __restrict__ gv2y,
    const float* __restrict__ ginv,
    const int* __restrict__ psize,
    unsigned long long* __restrict__ keybuf,
    int T, int ntx, int fpb) {
  int S = *psize;
  int tile = blockIdx.x / K;
  int rseg = blockIdx.x - tile * K;
  int tx = tile % ntx, ty = tile / ntx;
  int tid = threadIdx.x;
  int lane = tid & 63;
  int wid = tid >> 6;                        // wave -> rows [4w, 4w+4)
  int col = tid & (TILE - 1);
  int row = tid / TILE;
  int px_i = tx * TILE + col;
  int py_i = ty * TILE + row;
  float px = (float)px_i, py = (float)py_i;
  bool inimg = (px_i < S) && (py_i < S);
  unsigned long long bkey = ~0ULL;
  // wave pixel extent (float-exact small ints)
  float wxlo = (float)(tx * TILE), wxhi = (float)(tx * TILE + TILE - 1);
  float wylo = (float)(ty * TILE + wid * 4);
  float wyhi = wylo + 3.0f;

  int base = rseg * fpb;
  int lim = min(base + fpb, T);

  for (int g = base; g < lim; g += 64) {
    int fi = g + lane;
    bool in = fi < lim;
    float fx0 = in ? gx0[fi] : 3.0e38f;
    float fx1 = in ? gx1[fi] : -3.0e38f;
    float fy0 = in ? gy0[fi] : 3.0e38f;
    float fy1 = in ? gy1[fi] : -3.0e38f;
    bool ovb = (wxhi >= fx0) && (wxlo < fx1) && (wyhi >= fy0) && (wylo < fy1);
    bool ov = false;
    if (ovb) {
      // diamond interval filter over the clipped strip rectangle.
      // Conservative: reject ONLY on proven all-pixels-fail; NaN/inf -> pass.
      float q0x = gv0x[fi], q0y = gv0y[fi];
      float q1x = gv1x[fi], q1y = gv1y[fi];
      float q2x = gv2x[fi], q2y = gv2y[fi];
      float qinv = ginv[fi];
      float X0 = fmaxf(wxlo, fx0), X1 = fminf(wxhi, fx1);
      float Y0 = fmaxf(wylo, fy0), Y1 = fminf(wyhi, fy1);
      // corner terms (d0 = (v1x-px)(v2y-py) - (v2x-px)(v1y-py), affine)
      float A0 = q1x - X0, A1 = q1x - X1;
      float B0 = q2y - Y0, B1 = q2y - Y1;
      float C0 = q2x - X0, C1 = q2x - X1;
      float D0 = q1y - Y0, D1 = q1y - Y1;
      float E0 = q0y - Y0, E1 = q0y - Y1;
      float F0 = q0x - X0, F1 = q0x - X1;
      float p, q;
      p = A0 * B0; q = C0 * D0; float u00 = p - q; float su = fabsf(p) + fabsf(q);
      p = A0 * B1; q = C0 * D1; float u01 = p - q; su = fmaxf(su, fabsf(p) + fabsf(q));
      p = A1 * B0; q = C1 * D0; float u10 = p - q; su = fmaxf(su, fabsf(p) + fabsf(q));
      p = A1 * B1; q = C1 * D1; float u11 = p - q; su = fmaxf(su, fabsf(p) + fabsf(q));
      // d1 = (v2x-px)(v0y-py) - (v0x-px)(v2y-py)
      p = C0 * E0; q = F0 * B0; float v00 = p - q; float sv = fabsf(p) + fabsf(q);
      p = C0 * E1; q = F0 * B1; float v01 = p - q; sv = fmaxf(sv, fabsf(p) + fabsf(q));
      p = C1 * E0; q = F1 * B0; float v10 = p - q; sv = fmaxf(sv, fabsf(p) + fabsf(q));
      p = C1 * E1; q = F1 * B1; float v11 = p - q; sv = fmaxf(sv, fabsf(p) + fabsf(q));
      float epsU = 2e-6f * su;
      float epsV = 2e-6f * sv;
      float epsS = epsU + epsV;
      auto minabs4 = [](float x00, float x01, float x10, float x11, float eps) {
        float lo = fminf(fminf(x00, x01), fminf(x10, x11));
        float hi = fmaxf(fmaxf(x00, x01), fmaxf(x10, x11));
        float mres = 0.0f;
        if (lo > eps) mres = lo - eps;
        else if (hi < -eps) mres = -hi - eps;
        return mres;   // NaN inputs -> 0 (pass)
      };
      float m0 = minabs4(u00, u01, u10, u11, epsU);
      float m1 = minabs4(v00, v01, v10, v11, epsV);
      float msum = minabs4(u00 + v00, u01 + v01, u10 + v10, u11 + v11, epsS);
      float mdif = minabs4(u00 - v00, u01 - v01, u10 - v10, u11 - v11, epsS);
      float mm = fmaxf(msum, mdif);   // |d0|+|d1| >= max(|d0+d1|,|d0-d1|)
      float hv = 0.5f * qinv;
      bool rej = (m0 * hv > 1.0001f) || (m1 * hv > 1.0001f) || (mm * hv > 1.0001f);
      ov = !rej;
    }
    unsigned long long m = __ballot(ov);
    while (m) {
      // extract up to 4 hits; overlap their (wave-uniform) record loads
      int j0 = __builtin_ctzll(m); m &= m - 1;
      int j1 = -1, j2 = -1, j3 = -1;
      if (m) { j1 = __builtin_ctzll(m); m &= m - 1;
        if (m) { j2 = __builtin_ctzll(m); m &= m - 1;
          if (m) { j3 = __builtin_ctzll(m); m &= m - 1; } } }
      const float4* p0 = rec + 4 * (g + j0);
      const float4* p1 = rec + 4 * (g + (j1 >= 0 ? j1 : j0));
      const float4* p2 = rec + 4 * (g + (j2 >= 0 ? j2 : j0));
      const float4* p3 = rec + 4 * (g + (j3 >= 0 ? j3 : j0));
      float4 a0 = p0[0], a1 = p0[1], a2 = p0[2], a3 = p0[3];
      float4 b0 = p1[0], b1 = p1[1], b2 = p1[2], b3 = p1[3];
      float4 c0 = p2[0], c1 = p2[1], c2 = p2[2], c3 = p2[3];
      float4 d0 = p3[0], d1 = p3[1], d2 = p3[2], d3 = p3[3];

#define PROCESS(q0, q1, q2, q3, enable)                                        \
      if (enable) {                                                            \
        float v0x = q0.x, v0y = q0.y, v1x = q0.z, v1y = q0.w;                  \
        float v2x = q1.x, v2y = q1.y, x0 = q1.z, x1 = q1.w;                    \
        float y0 = q2.x, y1 = q2.y, inv = q2.z;                                \
        /* exact reference ops (no FMA): w0 = fl(fl(0.5*|d0|)*inv) */          \
        float e0 = __fsub_rn(__fmul_rn(__fsub_rn(v1x, px), __fsub_rn(v2y, py)),\
                             __fmul_rn(__fsub_rn(v2x, px), __fsub_rn(v1y, py)));\
        float w0 = __fmul_rn(__fmul_rn(0.5f, fabsf(e0)), inv);                 \
        float e1 = __fsub_rn(__fmul_rn(__fsub_rn(v2x, px), __fsub_rn(v0y, py)),\
                             __fmul_rn(__fsub_rn(v0x, px), __fsub_rn(v2y, py)));\
        float w1 = __fmul_rn(__fmul_rn(0.5f, fabsf(e1)), inv);                 \
        float w2 = __fsub_rn(__fsub_rn(1.0f, w0), w1);                         \
        bool ok = (w0 >= 0.0f) && (w1 >= 0.0f) && (w2 >= 0.0f) &&              \
                  (w0 <= 1.0f) && (w1 <= 1.0f) && (w2 <= 1.0f) &&              \
                  (px >= x0) && (px < x1) && (py >= y0) && (py < y1);          \
        unsigned long long fk =                                                \
            ((unsigned long long)__float_as_uint(q3.x) << 32) |                \
            __float_as_uint(q3.y);                                             \
        if (ok && fk < bkey) bkey = fk;                                        \
      }

      PROCESS(a0, a1, a2, a3, true)
      PROCESS(b0, b1, b2, b3, (j1 >= 0))
      PROCESS(c0, c1, c2, c3, (j2 >= 0))
      PROCESS(d0, d1, d2, d3, (j3 >= 0))
#undef PROCESS
    }
  }

  if (inimg && bkey != ~0ULL) {
    unsigned long long* kp = keybuf + ((size_t)py_i * (size_t)S + px_i);
    unsigned long long cur = *kp;     // racy pre-read: filter only
    if (bkey < cur) atomicMin(kp, bkey);
  }
}

__global__ void resolve_kernel(const unsigned long long* __restrict__ keybuf,
                               const float* __restrict__ colors,
                               float* __restrict__ out,
                               const int* __restrict__ psize) {
  int S = *psize;
  int P = S * S;
  int i = blockIdx.x * blockDim.x + threadIdx.x;
  if (i >= P) return;
  unsigned long long k = keybuf[i];
  float c = (k == 0xFFFFFFFFFFFFFFFFULL)
                ? 255.0f
                : colors[(unsigned)(k & 0xFFFFFFFFULL)];
  out[3 * i + 0] = c;
  out[3 * i + 1] = c;
  out[3 * i + 2] = c;
}

extern "C" void kernel_launch(void* const* d_in, const int* in_sizes, int n_in,
                              void* d_out, int out_size, void* d_ws, size_t ws_size,
                              hipStream_t stream) {
  const float* verts = (const float*)d_in[0];
  const int* faces = (const int*)d_in[1];
  const int* elev = (const int*)d_in[2];
  const int* azim = (const int*)d_in[3];
  const int* psize = (const int*)d_in[4];

  int N = in_sizes[0] / 3;   // 10000
  int T = in_sizes[1] / 3;   // 2048
  const int S_host = 500;    // harness-fixed; device kernels index via *psize
  const int P = S_host * S_host;
  const int ntx = (S_host + TILE - 1) / TILE;   // 32
  const int nty = (S_host + TILE - 1) / TILE;   // 32
  const int ntiles = ntx * nty;                 // 1024
  int fpb = (((T + K - 1) / K + 63) / 64) * 64; // faces per range segment

  float* wsf = (float*)d_ws;
  size_t off = 0;
  auto alloc = [&](size_t nfloats) {
    float* p = wsf + off;
    off += (nfloats + 15) & ~(size_t)15;
    return p;
  };
  float* vvx = alloc(N);
  float* vvy = alloc(N);
  float* vvz = alloc(N);
  float* vtx = alloc(N);
  float* vty = alloc(N);
  float* gx0 = alloc(T);
  float* gx1 = alloc(T);
  float* gy0 = alloc(T);
  float* gy1 = alloc(T);
  float* gv0x = alloc(T);
  float* gv0y = alloc(T);
  float* gv1x = alloc(T);
  float* gv1y = alloc(T);
  float* gv2x = alloc(T);
  float* gv2y = alloc(T);
  float* ginv = alloc(T);
  float* colors = alloc(T);
  float4* rec = (float4*)alloc((size_t)T * 16);
  unsigned long long* keybuf = (unsigned long long*)alloc((size_t)P * 2);

  vertex_kernel<<<(N + 255) / 256, 256, 0, stream>>>(verts, elev, azim,
                                                     vvx, vvy, vvz, vtx, vty, N, psize);
  face_kernel<<<(T + 255) / 256, 256, 0, stream>>>(faces, vvx, vvy, vvz, vtx, vty,
                                                   rec, gx0, gx1, gy0, gy1,
                                                   gv0x, gv0y, gv1x, gv1y, gv2x, gv2y,
                                                   ginv, colors, T, psize);
  hipMemsetAsync(keybuf, 0xFF, (size_t)P * 8, stream);
  raster_kernel<<<ntiles * K, 256, 0, stream>>>(rec, gx0, gx1, gy0, gy1,
                                                gv0x, gv0y, gv1x, gv1y, gv2x, gv2y,
                                                ginv, psize, keybuf, T, ntx, fpb);
  resolve_kernel<<<(P + 255) / 256, 256, 0, stream>>>(keybuf, colors,
                                                      (float*)d_out, psize);
}

// Round 8
// 87.106 us; speedup vs baseline: 3.3476x; 1.3478x over previous
//
#include <hip/hip_runtime.h>
#include <math.h>

// ---------------------------------------------------------------------------
// Unsorted, K-split, tile-parallel rasterizer + tile z-bound occlusion culling.
// Winner per pixel = min over exact-passing faces of (ordered_z_bits<<32)|idx
// == reference's strict-< chunk scan + argmin-first tie-break (absmax 0.0,
// R2-R7). Decision arithmetic: identical _rn op sequence, verbatim.
// R8 adds tilez_kernel: per 16x16 tile, find min zu over faces that PROVABLY
// cover the whole tile (interval-bounded max of w0,w1,w0+w1 <= 0.9999, tile
// inside bbox, finite coords). Faces with zu > bound can never win any pixel
// of the tile (lexicographic key dominance) -> skipped in the lane filter.
// Conservative everywhere: NaN/inf -> no cover claim / filter passes.
// ---------------------------------------------------------------------------

#define TILE 16
#define K    8      // range segments per tile

__device__ __forceinline__ void rot_matrix(int elev, int azim,
                                           float& r00, float& r01, float& r02,
                                           float& r11, float& r12,
                                           float& r20, float& r21, float& r22) {
  const float degf = (float)(3.14159265358979323846 / 180.0);
  float e = __fmul_rn((float)elev, degf);
  float a = __fmul_rn((float)azim, degf);
  float ca = (float)cos((double)a);
  float sa = (float)sin((double)a);
  float ce = (float)cos((double)e);
  float se = (float)sin((double)e);
  // R = rot_y @ rot_x; each entry a single product (exact vs any matmul order)
  r00 = ca;  r01 = __fmul_rn(sa, se); r02 = __fmul_rn(sa, ce);
  r11 = ce;  r12 = -se;
  r20 = -sa; r21 = __fmul_rn(ca, se); r22 = __fmul_rn(ca, ce);
}

__global__ void vertex_kernel(const float* __restrict__ verts,
                              const int* __restrict__ elev,
                              const int* __restrict__ azim,
                              float* __restrict__ vx, float* __restrict__ vy,
                              float* __restrict__ vz, float* __restrict__ vtx,
                              float* __restrict__ vty,
                              int N, const int* __restrict__ psize) {
  int i = blockIdx.x * blockDim.x + threadIdx.x;
  if (i >= N) return;
  float r00, r01, r02, r11, r12, r20, r21, r22;
  rot_matrix(*elev, *azim, r00, r01, r02, r11, r12, r20, r21, r22);
  float a0 = verts[3 * i + 0];
  float a1 = verts[3 * i + 1];
  float a2 = verts[3 * i + 2];
  // vr = v @ R, k-ascending, no FMA: ((m0+m1)+m2); r10 = 0
  float x = __fadd_rn(__fadd_rn(__fmul_rn(a0, r00), __fmul_rn(a1, 0.0f)), __fmul_rn(a2, r20));
  float y = __fadd_rn(__fadd_rn(__fmul_rn(a0, r01), __fmul_rn(a1, r11)), __fmul_rn(a2, r21));
  float z = __fadd_rn(__fadd_rn(__fmul_rn(a0, r02), __fmul_rn(a1, r12)), __fmul_rn(a2, r22));
  z = __fadd_rn(z, 2.0f);
  float halfS = (float)((double)(*psize) * 0.5);
  float sx = __fmul_rn(__fadd_rn(__fdiv_rn(x, z), 1.0f), halfS);
  float sy = __fmul_rn(__fadd_rn(__fdiv_rn(y, z), 1.0f), halfS);
  vx[i] = x;
  vy[i] = y;
  vz[i] = z;
  vtx[i] = truncf(sx);
  vty[i] = truncf(sy);
}

// rec layout (4x float4, 64B): {v0x,v0y,v1x,v1y} {v2x,v2y,x0,x1}
//                              {y0,y1,inv,col}   {bits(zu),bits(idx),0,0}
__global__ void face_kernel(const int* __restrict__ faces,
                            const float* __restrict__ vx, const float* __restrict__ vy,
                            const float* __restrict__ vz, const float* __restrict__ vtx,
                            const float* __restrict__ vty,
                            float4* __restrict__ rec,
                            float* __restrict__ gx0, float* __restrict__ gx1,
                            float* __restrict__ gy0, float* __restrict__ gy1,
                            float* __restrict__ gv0x, float* __restrict__ gv0y,
                            float* __restrict__ gv1x, float* __restrict__ gv1y,
                            float* __restrict__ gv2x, float* __restrict__ gv2y,
                            float* __restrict__ ginv, unsigned* __restrict__ gzu,
                            float* __restrict__ colors,
                            int T, const int* __restrict__ psize) {
  int t = blockIdx.x * blockDim.x + threadIdx.x;
  if (t >= T) return;
  int f0 = faces[3 * t + 0];
  int f1 = faces[3 * t + 1];
  int f2 = faces[3 * t + 2];
  float p0x = vx[f0], p0y = vy[f0], p0z = vz[f0];
  float p1x = vx[f1], p1y = vy[f1], p1z = vz[f1];
  float p2x = vx[f2], p2y = vy[f2], p2z = vz[f2];
  float e1x = __fsub_rn(p1x, p0x), e1y = __fsub_rn(p1y, p0y), e1z = __fsub_rn(p1z, p0z);
  float e2x = __fsub_rn(p2x, p0x), e2y = __fsub_rn(p2y, p0y), e2z = __fsub_rn(p2z, p0z);
  float nx = __fsub_rn(__fmul_rn(e1y, e2z), __fmul_rn(e1z, e2y));
  float ny = __fsub_rn(__fmul_rn(e1z, e2x), __fmul_rn(e1x, e2z));
  float nz = __fsub_rn(__fmul_rn(e1x, e2y), __fmul_rn(e1y, e2x));
  float nrm = __fsqrt_rn(__fadd_rn(__fadd_rn(__fmul_rn(nx, nx), __fmul_rn(ny, ny)),
                                   __fmul_rn(nz, nz)));
  float nnz = __fdiv_rn(nz, __fadd_rn(nrm, 1e-8f));
  float cl = fminf(fmaxf(nnz, 0.0f), 1.0f);
  float col = __fadd_rn(__fmul_rn(cl, 180.0f), 75.0f);
  float zf = __fdiv_rn(__fadd_rn(__fadd_rn(p0z, p1z), p2z), 3.0f);
  float t0x = vtx[f0], t0y = vty[f0];
  float t1x = vtx[f1], t1y = vty[f1];
  float t2x = vtx[f2], t2y = vty[f2];
  float cr = __fsub_rn(__fmul_rn(__fsub_rn(t1x, t0x), __fsub_rn(t2y, t0y)),
                       __fmul_rn(__fsub_rn(t2x, t0x), __fsub_rn(t1y, t0y)));
  float area = __fmul_rn(0.5f, fabsf(cr));
  bool valid = (area >= 1e-5f);   // NaN -> false, matches jnp
  float inv = __fdiv_rn(1.0f, __fadd_rn(area, 1e-8f));
  int S = *psize;
  float Sm1 = (float)(S - 1);
  float x0 = fmaxf(0.0f, fminf(fminf(t0x, t1x), t2x));
  float x1 = fminf(Sm1, __fadd_rn(fmaxf(fmaxf(t0x, t1x), t2x), 1.0f));
  float y0 = fmaxf(0.0f, fminf(fminf(t0y, t1y), t2y));
  float y1 = fminf(Sm1, __fadd_rn(fmaxf(fmaxf(t0y, t1y), t2y), 1.0f));
  unsigned zb = __float_as_uint(zf);
  unsigned zu = (zb & 0x80000000u) ? ~zb : (zb | 0x80000000u);
  if (!valid) x1 = -3.0e38f;   // exact skip: invalid faces never pass px < x1
  gx0[t] = x0; gx1[t] = x1; gy0[t] = y0; gy1[t] = y1;
  gv0x[t] = t0x; gv0y[t] = t0y;
  gv1x[t] = t1x; gv1y[t] = t1y;
  gv2x[t] = t2x; gv2y[t] = t2y;
  ginv[t] = inv;
  gzu[t] = zu;
  colors[t] = col;
  float4 r0, r1, r2, r3;
  r0.x = t0x; r0.y = t0y; r0.z = t1x; r0.w = t1y;
  r1.x = t2x; r1.y = t2y; r1.z = x0;  r1.w = x1;
  r2.x = y0;  r2.y = y1;  r2.z = inv; r2.w = col;
  r3.x = __uint_as_float(zu); r3.y = __uint_as_float((unsigned)t);
  r3.z = 0.0f; r3.w = 0.0f;
  rec[4 * t + 0] = r0;
  rec[4 * t + 1] = r1;
  rec[4 * t + 2] = r2;
  rec[4 * t + 3] = r3;
}

// Per-tile conservative z bound: min zu over faces PROVABLY covering the
// whole tile. max of |affine| over a rectangle is attained at the 4 corners;
// margins cover all fl rounding (see R7 filter, same magnitudes).
__global__ __launch_bounds__(64) void tilez_kernel(
    const float* __restrict__ gx0, const float* __restrict__ gx1,
    const float* __restrict__ gy0, const float* __restrict__ gy1,
    const float* __restrict__ gv0x, const float* __restrict__ gv0y,
    const float* __restrict__ gv1x, const float* __restrict__ gv1y,
    const float* __restrict__ gv2x, const float* __restrict__ gv2y,
    const float* __restrict__ ginv, const unsigned* __restrict__ gzu,
    unsigned* __restrict__ tilezu, int T, int ntx) {
  int tile = blockIdx.x;
  int lane = threadIdx.x;
  int tx = tile % ntx, ty = tile / ntx;
  float X0 = (float)(tx * TILE), X1 = (float)(tx * TILE + TILE - 1);
  float Y0 = (float)(ty * TILE), Y1 = (float)(ty * TILE + TILE - 1);
  unsigned best = 0xFFFFFFFFu;
  for (int g = lane; g < T; g += 64) {
    float x0 = gx0[g], x1 = gx1[g], y0 = gy0[g], y1 = gy1[g];
    // tile inside bbox (px>=x0, px<x1, py>=y0, py<y1 for ALL tile pixels)
    if (!(X0 >= x0 && X1 < x1 && Y0 >= y0 && Y1 < y1)) continue;
    float q0x = gv0x[g], q0y = gv0y[g];
    float q1x = gv1x[g], q1y = gv1y[g];
    float q2x = gv2x[g], q2y = gv2y[g];
    // finite guard: products below stay finite -> no NaN in max/eps chain
    bool fin = fabsf(q0x) < 1e17f && fabsf(q0y) < 1e17f &&
               fabsf(q1x) < 1e17f && fabsf(q1y) < 1e17f &&
               fabsf(q2x) < 1e17f && fabsf(q2y) < 1e17f;
    if (!fin) continue;
    float qinv = ginv[g];
    float A0 = q1x - X0, A1 = q1x - X1, B0 = q2y - Y0, B1 = q2y - Y1;
    float C0 = q2x - X0, C1 = q2x - X1, D0 = q1y - Y0, D1 = q1y - Y1;
    float E0 = q0y - Y0, E1 = q0y - Y1, F0 = q0x - X0, F1 = q0x - X1;
    float p, q;
    p = A0 * B0; q = C0 * D0; float u00 = p - q; float su = fabsf(p) + fabsf(q);
    p = A0 * B1; q = C0 * D1; float u01 = p - q; su = fmaxf(su, fabsf(p) + fabsf(q));
    p = A1 * B0; q = C1 * D0; float u10 = p - q; su = fmaxf(su, fabsf(p) + fabsf(q));
    p = A1 * B1; q = C1 * D1; float u11 = p - q; su = fmaxf(su, fabsf(p) + fabsf(q));
    p = C0 * E0; q = F0 * B0; float v00 = p - q; float sv = fabsf(p) + fabsf(q);
    p = C0 * E1; q = F0 * B1; float v01 = p - q; sv = fmaxf(sv, fabsf(p) + fabsf(q));
    p = C1 * E0; q = F1 * B0; float v10 = p - q; sv = fmaxf(sv, fabsf(p) + fabsf(q));
    p = C1 * E1; q = F1 * B1; float v11 = p - q; sv = fmaxf(sv, fabsf(p) + fabsf(q));
    float umax = fmaxf(fmaxf(fabsf(u00), fabsf(u01)), fmaxf(fabsf(u10), fabsf(u11)));
    float vmax = fmaxf(fmaxf(fabsf(v00), fabsf(v01)), fmaxf(fabsf(v10), fabsf(v11)));
    float epsU = 2e-6f * su, epsV = 2e-6f * sv;
    float hv = 0.5f * qinv;
    bool cover = ((umax + epsU) * hv <= 0.9999f) &&
                 ((vmax + epsV) * hv <= 0.9999f) &&
                 ((umax + vmax + epsU + epsV) * hv <= 0.9999f);
    if (cover) best = min(best, gzu[g]);
  }
  for (int o = 32; o > 0; o >>= 1)
    best = min(best, (unsigned)__shfl_down((int)best, o));
  if (lane == 0) tilezu[tile] = best;
}

__global__ __launch_bounds__(256) void raster_kernel(
    const float4* __restrict__ rec,
    const float* __restrict__ gx0, const float* __restrict__ gx1,
    const float* __restrict__ gy0, const float* __restrict__ gy1,
    const float* __restrict__ gv0x, const float* __restrict__ gv0y,
    const float* __restrict__ gv1x, const float* __restrict__ gv1y,
    const float* __restrict__ gv2x, const float* __restrict__ gv2y,
    const float* __restrict__ ginv, const unsigned* __restrict__ gzu,
    const unsigned* __restrict__ tilezu,
    const int* __restrict__ psize,
    unsigned long long* __restrict__ keybuf,
    int T, int ntx, int fpb) {
  int S = *psize;
  int tile = blockIdx.x / K;
  int rseg = blockIdx.x - tile * K;
  int tx = tile % ntx, ty = tile / ntx;
  int tid = threadIdx.x;
  int lane = tid & 63;
  int wid = tid >> 6;                        // wave -> rows [4w, 4w+4)
  int col = tid & (TILE - 1);
  int row = tid / TILE;
  int px_i = tx * TILE + col;
  int py_i = ty * TILE + row;
  float px = (float)px_i, py = (float)py_i;
  bool inimg = (px_i < S) && (py_i < S);
  unsigned long long bkey = ~0ULL;
  unsigned tzu = tilezu[tile];               // occlusion bound for this tile
  // wave pixel extent (float-exact small ints)
  float wxlo = (float)(tx * TILE), wxhi = (float)(tx * TILE + TILE - 1);
  float wylo = (float)(ty * TILE + wid * 4);
  float wyhi = wylo + 3.0f;

  int base = rseg * fpb;
  int lim = min(base + fpb, T);

  for (int g = base; g < lim; g += 64) {
    int fi = g + lane;
    bool in = fi < lim;
    float fx0 = in ? gx0[fi] : 3.0e38f;
    float fx1 = in ? gx1[fi] : -3.0e38f;
    float fy0 = in ? gy0[fi] : 3.0e38f;
    float fy1 = in ? gy1[fi] : -3.0e38f;
    unsigned fzu = in ? gzu[fi] : 0xFFFFFFFFu;
    bool ovb = (wxhi >= fx0) && (wxlo < fx1) && (wyhi >= fy0) && (wylo < fy1) &&
               (fzu <= tzu);   // occlusion cull: zu>bound can't win any pixel
    bool ov = false;
    if (ovb) {
      // diamond interval filter over the clipped strip rectangle.
      // Conservative: reject ONLY on proven all-pixels-fail; NaN/inf -> pass.
      float q0x = gv0x[fi], q0y = gv0y[fi];
      float q1x = gv1x[fi], q1y = gv1y[fi];
      float q2x = gv2x[fi], q2y = gv2y[fi];
      float qinv = ginv[fi];
      bool fin = fabsf(q0x) < 1e17f && fabsf(q0y) < 1e17f &&
                 fabsf(q1x) < 1e17f && fabsf(q1y) < 1e17f &&
                 fabsf(q2x) < 1e17f && fabsf(q2y) < 1e17f;
      float X0 = fmaxf(wxlo, fx0), X1 = fminf(wxhi, fx1);
      float Y0 = fmaxf(wylo, fy0), Y1 = fminf(wyhi, fy1);
      float A0 = q1x - X0, A1 = q1x - X1;
      float B0 = q2y - Y0, B1 = q2y - Y1;
      float C0 = q2x - X0, C1 = q2x - X1;
      float D0 = q1y - Y0, D1 = q1y - Y1;
      float E0 = q0y - Y0, E1 = q0y - Y1;
      float F0 = q0x - X0, F1 = q0x - X1;
      float p, q;
      p = A0 * B0; q = C0 * D0; float u00 = p - q; float su = fabsf(p) + fabsf(q);
      p = A0 * B1; q = C0 * D1; float u01 = p - q; su = fmaxf(su, fabsf(p) + fabsf(q));
      p = A1 * B0; q = C1 * D0; float u10 = p - q; su = fmaxf(su, fabsf(p) + fabsf(q));
      p = A1 * B1; q = C1 * D1; float u11 = p - q; su = fmaxf(su, fabsf(p) + fabsf(q));
      p = C0 * E0; q = F0 * B0; float v00 = p - q; float sv = fabsf(p) + fabsf(q);
      p = C0 * E1; q = F0 * B1; float v01 = p - q; sv = fmaxf(sv, fabsf(p) + fabsf(q));
      p = C1 * E0; q = F1 * B0; float v10 = p - q; sv = fmaxf(sv, fabsf(p) + fabsf(q));
      p = C1 * E1; q = F1 * B1; float v11 = p - q; sv = fmaxf(sv, fabsf(p) + fabsf(q));
      float epsU = 2e-6f * su;
      float epsV = 2e-6f * sv;
      float epsS = epsU + epsV;
      auto minabs4 = [](float x00, float x01, float x10, float x11, float eps) {
        float lo = fminf(fminf(x00, x01), fminf(x10, x11));
        float hi = fmaxf(fmaxf(x00, x01), fmaxf(x10, x11));
        float mres = 0.0f;
        if (lo > eps) mres = lo - eps;
        else if (hi < -eps) mres = -hi - eps;
        return mres;   // NaN inputs -> 0 (pass)
      };
      float m0 = minabs4(u00, u01, u10, u11, epsU);
      float m1 = minabs4(v00, v01, v10, v11, epsV);
      float msum = minabs4(u00 + v00, u01 + v01, u10 + v10, u11 + v11, epsS);
      float mdif = minabs4(u00 - v00, u01 - v01, u10 - v10, u11 - v11, epsS);
      float mm = fmaxf(msum, mdif);   // |d0|+|d1| >= max(|d0+d1|,|d0-d1|)
      float hv = 0.5f * qinv;
      bool rej = fin && ((m0 * hv > 1.0001f) || (m1 * hv > 1.0001f) ||
                         (mm * hv > 1.0001f));
      ov = !rej;
    }
    unsigned long long m = __ballot(ov);
    while (m) {
      // extract up to 4 hits; overlap their (wave-uniform) record loads
      int j0 = __builtin_ctzll(m); m &= m - 1;
      int j1 = -1, j2 = -1, j3 = -1;
      if (m) { j1 = __builtin_ctzll(m); m &= m - 1;
        if (m) { j2 = __builtin_ctzll(m); m &= m - 1;
          if (m) { j3 = __builtin_ctzll(m); m &= m - 1; } } }
      const float4* p0 = rec + 4 * (g + j0);
      const float4* p1 = rec + 4 * (g + (j1 >= 0 ? j1 : j0));
      const float4* p2 = rec + 4 * (g + (j2 >= 0 ? j2 : j0));
      const float4* p3 = rec + 4 * (g + (j3 >= 0 ? j3 : j0));
      float4 a0 = p0[0], a1 = p0[1], a2 = p0[2], a3 = p0[3];
      float4 b0 = p1[0], b1 = p1[1], b2 = p1[2], b3 = p1[3];
      float4 c0 = p2[0], c1 = p2[1], c2 = p2[2], c3 = p2[3];
      float4 d0 = p3[0], d1 = p3[1], d2 = p3[2], d3 = p3[3];

#define PROCESS(q0, q1, q2, q3, enable)                                        \
      if (enable) {                                                            \
        float v0x = q0.x, v0y = q0.y, v1x = q0.z, v1y = q0.w;                  \
        float v2x = q1.x, v2y = q1.y, x0 = q1.z, x1 = q1.w;                    \
        float y0 = q2.x, y1 = q2.y, inv = q2.z;                                \
        /* exact reference ops (no FMA): w0 = fl(fl(0.5*|d0|)*inv) */          \
        float e0 = __fsub_rn(__fmul_rn(__fsub_rn(v1x, px), __fsub_rn(v2y, py)),\
                             __fmul_rn(__fsub_rn(v2x, px), __fsub_rn(v1y, py)));\
        float w0 = __fmul_rn(__fmul_rn(0.5f, fabsf(e0)), inv);                 \
        float e1 = __fsub_rn(__fmul_rn(__fsub_rn(v2x, px), __fsub_rn(v0y, py)),\
                             __fmul_rn(__fsub_rn(v0x, px), __fsub_rn(v2y, py)));\
        float w1 = __fmul_rn(__fmul_rn(0.5f, fabsf(e1)), inv);                 \
        float w2 = __fsub_rn(__fsub_rn(1.0f, w0), w1);                         \
        bool ok = (w0 >= 0.0f) && (w1 >= 0.0f) && (w2 >= 0.0f) &&              \
                  (w0 <= 1.0f) && (w1 <= 1.0f) && (w2 <= 1.0f) &&              \
                  (px >= x0) && (px < x1) && (py >= y0) && (py < y1);          \
        unsigned long long fk =                                                \
            ((unsigned long long)__float_as_uint(q3.x) << 32) |                \
            __float_as_uint(q3.y);                                             \
        if (ok && fk < bkey) bkey = fk;                                        \
      }

      PROCESS(a0, a1, a2, a3, true)
      PROCESS(b0, b1, b2, b3, (j1 >= 0))
      PROCESS(c0, c1, c2, c3, (j2 >= 0))
      PROCESS(d0, d1, d2, d3, (j3 >= 0))
#undef PROCESS
    }
  }

  if (inimg && bkey != ~0ULL) {
    unsigned long long* kp = keybuf + ((size_t)py_i * (size_t)S + px_i);
    unsigned long long cur = *kp;     // racy pre-read: filter only
    if (bkey < cur) atomicMin(kp, bkey);
  }
}

__global__ void resolve_kernel(const unsigned long long* __restrict__ keybuf,
                               const float* __restrict__ colors,
                               float* __restrict__ out,
                               const int* __restrict__ psize) {
  int S = *psize;
  int P = S * S;
  int i = blockIdx.x * blockDim.x + threadIdx.x;
  if (i >= P) return;
  unsigned long long k = keybuf[i];
  float c = (k == 0xFFFFFFFFFFFFFFFFULL)
                ? 255.0f
                : colors[(unsigned)(k & 0xFFFFFFFFULL)];
  out[3 * i + 0] = c;
  out[3 * i + 1] = c;
  out[3 * i + 2] = c;
}

extern "C" void kernel_launch(void* const* d_in, const int* in_sizes, int n_in,
                              void* d_out, int out_size, void* d_ws, size_t ws_size,
                              hipStream_t stream) {
  const float* verts = (const float*)d_in[0];
  const int* faces = (const int*)d_in[1];
  const int* elev = (const int*)d_in[2];
  const int* azim = (const int*)d_in[3];
  const int* psize = (const int*)d_in[4];

  int N = in_sizes[0] / 3;   // 10000
  int T = in_sizes[1] / 3;   // 2048
  const int S_host = 500;    // harness-fixed; device kernels index via *psize
  const int P = S_host * S_host;
  const int ntx = (S_host + TILE - 1) / TILE;   // 32
  const int nty = (S_host + TILE - 1) / TILE;   // 32
  const int ntiles = ntx * nty;                 // 1024
  int fpb = (((T + K - 1) / K + 63) / 64) * 64; // faces per range segment

  float* wsf = (float*)d_ws;
  size_t off = 0;
  auto alloc = [&](size_t nfloats) {
    float* p = wsf + off;
    off += (nfloats + 15) & ~(size_t)15;
    return p;
  };
  float* vvx = alloc(N);
  float* vvy = alloc(N);
  float* vvz = alloc(N);
  float* vtx = alloc(N);
  float* vty = alloc(N);
  float* gx0 = alloc(T);
  float* gx1 = alloc(T);
  float* gy0 = alloc(T);
  float* gy1 = alloc(T);
  float* gv0x = alloc(T);
  float* gv0y = alloc(T);
  float* gv1x = alloc(T);
  float* gv1y = alloc(T);
  float* gv2x = alloc(T);
  float* gv2y = alloc(T);
  float* ginv = alloc(T);
  unsigned* gzu = (unsigned*)alloc(T);
  float* colors = alloc(T);
  unsigned* tilezu = (unsigned*)alloc(ntiles);
  float4* rec = (float4*)alloc((size_t)T * 16);
  unsigned long long* keybuf = (unsigned long long*)alloc((size_t)P * 2);

  vertex_kernel<<<(N + 255) / 256, 256, 0, stream>>>(verts, elev, azim,
                                                     vvx, vvy, vvz, vtx, vty, N, psize);
  face_kernel<<<(T + 255) / 256, 256, 0, stream>>>(faces, vvx, vvy, vvz, vtx, vty,
                                                   rec, gx0, gx1, gy0, gy1,
                                                   gv0x, gv0y, gv1x, gv1y, gv2x, gv2y,
                                                   ginv, gzu, colors, T, psize);
  hipMemsetAsync(keybuf, 0xFF, (size_t)P * 8, stream);
  tilez_kernel<<<ntiles, 64, 0, stream>>>(gx0, gx1, gy0, gy1,
                                          gv0x, gv0y, gv1x, gv1y, gv2x, gv2y,
                                          ginv, gzu, tilezu, T, ntx);
  raster_kernel<<<ntiles * K, 256, 0, stream>>>(rec, gx0, gx1, gy0, gy1,
                                                gv0x, gv0y, gv1x, gv1y, gv2x, gv2y,
                                                ginv, gzu, tilezu, psize, keybuf,
                                                T, ntx, fpb);
  resolve_kernel<<<(P + 255) / 256, 256, 0, stream>>>(keybuf, colors,
                                                      (float*)d_out, psize);
}